// Round 7
// baseline (863.430 us; speedup 1.0000x reference)
//
#include <hip/hip_runtime.h>
#include <hip/hip_bf16.h>
#include <cstdint>

#define S_SEQ   2048
#define HID     4096
#define NQH     32
#define NKVH    8
#define DH      128
#define QKV_LD  6144      // (32+16)*128
#define SCALE_F 0.08838834764831845f
// softmax in log2 domain: s' = s * SCALE * log2(e)
#define C2F (0.08838834764831845f * 1.4426950408889634f)

using f32x4  = __attribute__((ext_vector_type(4))) float;
using f32x16 = __attribute__((ext_vector_type(16))) float;
using bf16x8 = __attribute__((ext_vector_type(8))) __bf16;
using u32x2  = __attribute__((ext_vector_type(2))) unsigned;

#define GLOAD_LDS16(gp, lp)                                                   \
  __builtin_amdgcn_global_load_lds(                                           \
      (__attribute__((address_space(1))) const void*)(gp),                    \
      (__attribute__((address_space(3))) void*)(lp), 16, 0, 0)

__device__ __forceinline__ unsigned short f2bf_bits(float f) {
  __hip_bfloat16 b = __float2bfloat16(f);
  return __builtin_bit_cast(unsigned short, b);
}

// permlane32_swap: X[32..63] <-> Y[0..31].
// lo lane: X'=own X, Y'=partner's X.  hi lane: X'=partner's Y, Y'=own Y.
__device__ __forceinline__ void plswap(unsigned& x, unsigned& y) {
  u32x2 r = __builtin_amdgcn_permlane32_swap(x, y, false, false);
  x = r[0];
  y = r[1];
}
// value of the partner lane (l ^ 32)
__device__ __forceinline__ float xhalf(float v, int hiP) {
  unsigned u = __builtin_bit_cast(unsigned, v);
  u32x2 r = __builtin_amdgcn_permlane32_swap(u, u, false, false);
  return __builtin_bit_cast(float, hiP ? r[0] : r[1]);
}

// ---------------------------------------------------------------------------
// f32 -> bf16 conversion (vectorized, grid-stride)
// ---------------------------------------------------------------------------
__global__ void cvt_f32_bf16(const float* __restrict__ in,
                             __hip_bfloat16* __restrict__ out, int n) {
  int i = blockIdx.x * blockDim.x + threadIdx.x;
  int stride = gridDim.x * blockDim.x;
  for (int e = i * 4; e < n; e += stride * 4) {
    float4 v = *(const float4*)(in + e);
    ushort4 u;
    u.x = f2bf_bits(v.x); u.y = f2bf_bits(v.y);
    u.z = f2bf_bits(v.z); u.w = f2bf_bits(v.w);
    *reinterpret_cast<ushort4*>(reinterpret_cast<unsigned short*>(out) + e) = u;
  }
}

// ---------------------------------------------------------------------------
// GEMM: C[M,N] = A[M,K] * B[N,K]^T   (both bf16, B^T layout)  (m97 structure)
// + bijective XCD swizzle on the flattened block id (grids are %8 == 0).
// ---------------------------------------------------------------------------
template <bool OUT_BF16>
__global__ __launch_bounds__(256) void gemm_bt_kernel(
    const __hip_bfloat16* __restrict__ A, const __hip_bfloat16* __restrict__ B,
    void* __restrict__ Cv, int M, int N, int K) {
  __shared__ __hip_bfloat16 sA[128 * 32];
  __shared__ __hip_bfloat16 sB[128 * 32];
  const int tid = threadIdx.x;
  const int w = tid >> 6, l = tid & 63;
  const int wr = w >> 1, wc = w & 1;
  const int lr = l & 15, lk = (l >> 4) << 3;

  const int nbx = gridDim.x;
  const int nwg = nbx * gridDim.y;
  int wgid = blockIdx.y * nbx + blockIdx.x;
  wgid = (wgid & 7) * (nwg >> 3) + (wgid >> 3);  // XCD chunking
  const int brow = (wgid / nbx) * 128;
  const int bcol = (wgid % nbx) * 128;

  f32x4 acc[4][4];
#pragma unroll
  for (int m = 0; m < 4; m++)
#pragma unroll
    for (int n = 0; n < 4; n++) acc[m][n] = (f32x4){0.f, 0.f, 0.f, 0.f};

  const int r0 = tid >> 2;
  const int c0 = (tid & 3) << 3;
  const __hip_bfloat16* Ag = A + (size_t)(brow + r0) * K + c0;
  const __hip_bfloat16* Bg = B + (size_t)(bcol + r0) * K + c0;

  for (int k0 = 0; k0 < K; k0 += 32) {
    GLOAD_LDS16(Ag + k0,                  sA + tid * 8);
    GLOAD_LDS16(Ag + k0 + (size_t)64 * K, sA + 2048 + tid * 8);
    GLOAD_LDS16(Bg + k0,                  sB + tid * 8);
    GLOAD_LDS16(Bg + k0 + (size_t)64 * K, sB + 2048 + tid * 8);
    __syncthreads();

    bf16x8 af[4], bfr[4];
#pragma unroll
    for (int m = 0; m < 4; m++)
      af[m] = *(const bf16x8*)&sA[(wr * 64 + m * 16 + lr) * 32 + lk];
#pragma unroll
    for (int n = 0; n < 4; n++)
      bfr[n] = *(const bf16x8*)&sB[(wc * 64 + n * 16 + lr) * 32 + lk];
#pragma unroll
    for (int m = 0; m < 4; m++)
#pragma unroll
      for (int n = 0; n < 4; n++)
        acc[m][n] = __builtin_amdgcn_mfma_f32_16x16x32_bf16(af[m], bfr[n],
                                                            acc[m][n], 0, 0, 0);
    __syncthreads();
  }

  const int jr = (l >> 4) << 2;
  if (OUT_BF16) {
    __hip_bfloat16* C = (__hip_bfloat16*)Cv;
#pragma unroll
    for (int m = 0; m < 4; m++)
#pragma unroll
      for (int n = 0; n < 4; n++)
#pragma unroll
        for (int j = 0; j < 4; j++) {
          size_t row = brow + wr * 64 + m * 16 + jr + j;
          size_t col = bcol + wc * 64 + n * 16 + lr;
          C[row * N + col] = __float2bfloat16(acc[m][n][j]);
        }
  } else {
    float* C = (float*)Cv;
#pragma unroll
    for (int m = 0; m < 4; m++)
#pragma unroll
      for (int n = 0; n < 4; n++)
#pragma unroll
        for (int j = 0; j < 4; j++) {
          size_t row = brow + wr * 64 + m * 16 + jr + j;
          size_t col = bcol + wc * 64 + n * 16 + lr;
          C[row * N + col] = acc[m][n][j];
        }
  }
}

// ---------------------------------------------------------------------------
// RoPE (neox) in-place on Q (heads 0..31) and K (heads 32..39) of QKV.
// ---------------------------------------------------------------------------
__global__ void rope_kernel(__hip_bfloat16* __restrict__ QKV,
                            const int* __restrict__ pos) {
  int idx = blockIdx.x * blockDim.x + threadIdx.x;  // S*40*64 total
  int d = idx & 63;
  int head = (idx >> 6) % 40;
  int s = idx / (64 * 40);
  float p = (float)pos[s];
  float inv = exp2f(-(float)d * 0.2076205059304297f);
  float fr = p * inv;
  float sn, cs;
  sincosf(fr, &sn, &cs);
  size_t base = (size_t)s * QKV_LD + head * 128 + d;
  float x1 = __bfloat162float(QKV[base]);
  float x2 = __bfloat162float(QKV[base + 64]);
  QKV[base]      = __float2bfloat16(x1 * cs - x2 * sn);
  QKV[base + 64] = __float2bfloat16(x2 * cs + x1 * sn);
}

// ---------------------------------------------------------------------------
// V transpose: Vt[kvh][d][s] = QKV[s][5120 + kvh*128 + d]
// ---------------------------------------------------------------------------
__global__ void vtrans_kernel(const __hip_bfloat16* __restrict__ QKV,
                              __hip_bfloat16* __restrict__ Vt) {
  int idx = blockIdx.x * blockDim.x + threadIdx.x;  // 8*128*2048
  int s = idx & 2047;
  int d = (idx >> 11) & 127;
  int kh = idx >> 18;
  Vt[idx] = QKV[(size_t)s * QKV_LD + 5120 + kh * 128 + d];
}

// ---------------------------------------------------------------------------
// Causal GQA flash attention, v6: swapped-QK 32x32 zero-LDS tiles
// + split-KV x2 (flash-decoding) for 2x occupancy.
//
// Block = (kvh, head-pair, qt): warps 0,1 = heads hp*2+{0,1}, kv tiles
// [0, nt/2); warps 2,3 = same heads, kv tiles [nt/2, nt) incl. diagonal.
// Half-1 warps publish (oacc, m, lsum) to LDS; one barrier; half-0 warps
// merge (standard online-softmax combine) and write O.
// Grid 1024 = 8 kvh x 2 hp x 64 qt (longest-first), 4 blocks/CU.
//
// mfma_f32_32x32x16_bf16 layouts:
//   A-frag: lane l holds A[row = l&31][k = (l>>5)*8 + j], j=0..7
//   B-frag: lane l holds B[k = (l>>5)*8 + j][col = l&31]
//   C/D:    lane l holds D[row = (r&3)+8*(r>>2)+4*(l>>5)][col = l&31], r=0..15
// ---------------------------------------------------------------------------
__global__ __launch_bounds__(256, 4) void attn_kernel(
    const __hip_bfloat16* __restrict__ QKV,
    const __hip_bfloat16* __restrict__ Vt, __hip_bfloat16* __restrict__ O) {
  __shared__ float Ms[2][64][67];  // [head-slot][lane][64 oacc + m + lsum]
  const int tid = threadIdx.x;
  const int w = tid >> 6, l = tid & 63;
  const int l31 = l & 31;
  const int hiP = l >> 5;
  const int bid = blockIdx.x;
  const int kvh = bid & 7;                 // XCD-resident kv head
  const int hp = (bid >> 3) & 1;           // head pair within kv group
  const int qt = 63 - (bid >> 4);          // longest blocks dispatched first
  const int half = w >> 1;                 // kv-range half
  const int h = kvh * 4 + hp * 2 + (w & 1);
  const int qwb = qt * 32;                 // q base row
  const int qg = qwb + l31;                // this lane's q row

  const __hip_bfloat16* Qp = QKV + (size_t)h * DH;
  const __hip_bfloat16* Kp = QKV + 4096 + (size_t)kvh * DH;
  const __hip_bfloat16* Vp = Vt + (size_t)kvh * (DH * S_SEQ);

  // Q B-frags (held whole kernel): qf[ks] = Q[q=l31][ks*16 + hiP*8 .. +8]
  bf16x8 qf[8];
  {
    const __hip_bfloat16* qrow = Qp + (size_t)(qwb + l31) * QKV_LD + hiP * 8;
#pragma unroll
    for (int ks = 0; ks < 8; ks++) qf[ks] = *(const bf16x8*)(qrow + ks * 16);
  }

  f32x16 oacc[4];
#pragma unroll
  for (int db = 0; db < 4; db++)
#pragma unroll
    for (int r = 0; r < 16; r++) oacc[db][r] = 0.f;
  float m = -1e30f, lsum = 0.f;

#define LOAD_KV(KF, VF, KB)                                                    \
  {                                                                            \
    const int lb_ = (KB);                                                      \
    const __hip_bfloat16* krow = Kp + (size_t)(lb_ + l31) * QKV_LD + hiP * 8;  \
    _Pragma("unroll") for (int ks = 0; ks < 8; ks++) KF[ks] =                  \
        *(const bf16x8*)(krow + ks * 16);                                      \
    _Pragma("unroll") for (int db = 0; db < 4; db++)                           \
        _Pragma("unroll") for (int k2 = 0; k2 < 2; k2++) VF[db][k2] =          \
        *(const bf16x8*)(Vp + (size_t)(db * 32 + l31) * S_SEQ + lb_ +          \
                         k2 * 16 + hiP * 8);                                   \
  }

#define COMPUTE_TILE(KF, VF, KB, MASKED)                                       \
  {                                                                            \
    const int kb_ = (KB);                                                      \
    f32x16 sacc;                                                               \
    _Pragma("unroll") for (int r = 0; r < 16; r++) sacc[r] = 0.f;              \
    _Pragma("unroll") for (int ks = 0; ks < 8; ks++) sacc =                    \
        __builtin_amdgcn_mfma_f32_32x32x16_bf16(KF[ks], qf[ks], sacc, 0, 0, 0);\
    float s[16];                                                               \
    _Pragma("unroll") for (int r = 0; r < 16; r++) s[r] = sacc[r] * C2F;       \
    if (MASKED) {                                                              \
      _Pragma("unroll") for (int r = 0; r < 16; r++) {                         \
        const int kvg = kb_ + (r & 3) + 8 * (r >> 2) + 4 * hiP;                \
        s[r] = (kvg <= qg) ? s[r] : -1e30f;                                    \
      }                                                                        \
    }                                                                          \
    float m0 = fmaxf(fmaxf(s[0], s[1]), fmaxf(s[2], s[3]));                    \
    float m1 = fmaxf(fmaxf(s[4], s[5]), fmaxf(s[6], s[7]));                    \
    float m2 = fmaxf(fmaxf(s[8], s[9]), fmaxf(s[10], s[11]));                  \
    float m3 = fmaxf(fmaxf(s[12], s[13]), fmaxf(s[14], s[15]));                \
    float rmax = fmaxf(fmaxf(m0, m1), fmaxf(m2, m3));                          \
    rmax = fmaxf(rmax, xhalf(rmax, hiP));                                      \
    if (__any(rmax - m > 8.0f)) {                                              \
      float mn = fmaxf(m, rmax);                                               \
      float sc = __builtin_amdgcn_exp2f(m - mn);                               \
      lsum *= sc;                                                              \
      _Pragma("unroll") for (int db = 0; db < 4; db++)                         \
          _Pragma("unroll") for (int r = 0; r < 16; r++) oacc[db][r] *= sc;    \
      m = mn;                                                                  \
    }                                                                          \
    float p[16];                                                               \
    _Pragma("unroll") for (int r = 0; r < 16; r++) p[r] =                      \
        __builtin_amdgcn_exp2f(s[r] - m);                                      \
    float rs = ((p[0] + p[1]) + (p[2] + p[3])) +                               \
               ((p[4] + p[5]) + (p[6] + p[7])) +                               \
               ((p[8] + p[9]) + (p[10] + p[11])) +                             \
               ((p[12] + p[13]) + (p[14] + p[15]));                            \
    lsum += rs + xhalf(rs, hiP);                                               \
    unsigned Wp[8];                                                            \
    _Pragma("unroll") for (int i = 0; i < 8; i++) Wp[i] =                      \
        (unsigned)f2bf_bits(p[2 * i]) |                                        \
        ((unsigned)f2bf_bits(p[2 * i + 1]) << 16);                             \
    unsigned s0x = Wp[0], s0y = Wp[2];                                         \
    unsigned s1x = Wp[1], s1y = Wp[3];                                         \
    unsigned s2x = Wp[4], s2y = Wp[6];                                         \
    unsigned s3x = Wp[5], s3y = Wp[7];                                         \
    plswap(s0x, s0y);                                                          \
    plswap(s1x, s1y);                                                          \
    plswap(s2x, s2y);                                                          \
    plswap(s3x, s3y);                                                          \
    int4 f0, f1;                                                               \
    f0.x = (int)s0x; f0.y = (int)s1x; f0.z = (int)s0y; f0.w = (int)s1y;        \
    f1.x = (int)s2x; f1.y = (int)s3x; f1.z = (int)s2y; f1.w = (int)s3y;        \
    bf16x8 pfrag[2];                                                           \
    pfrag[0] = __builtin_bit_cast(bf16x8, f0);                                 \
    pfrag[1] = __builtin_bit_cast(bf16x8, f1);                                 \
    _Pragma("unroll") for (int db = 0; db < 4; db++)                           \
        _Pragma("unroll") for (int k2 = 0; k2 < 2; k2++) oacc[db] =            \
        __builtin_amdgcn_mfma_f32_32x32x16_bf16(VF[db][k2], pfrag[k2],         \
                                                oacc[db], 0, 0, 0);            \
  }

  const int nt = qt + 1;
  const int nt0 = nt >> 1;  // tiles in half 0 (may be 0)
  bf16x8 kA[8], kB[8];
  bf16x8 vA[4][2], vB[4][2];

  if (half) {
    // tiles [nt0, nt), last one (base qwb) masked
    const int kbeg = nt0 * 32;
    LOAD_KV(kA, vA, kbeg);
    int kb = kbeg;
    for (; kb + 64 <= qwb; kb += 64) {
      LOAD_KV(kB, vB, kb + 32);
      COMPUTE_TILE(kA, vA, kb, false);
      LOAD_KV(kA, vA, kb + 64);
      COMPUTE_TILE(kB, vB, kb + 32, false);
    }
    if (kb < qwb) {
      LOAD_KV(kB, vB, qwb);
      COMPUTE_TILE(kA, vA, kb, false);
      COMPUTE_TILE(kB, vB, qwb, true);
    } else {
      COMPUTE_TILE(kA, vA, qwb, true);
    }
  } else if (nt0 > 0) {
    // tiles [0, nt0), all full
    const int kend = nt0 * 32;  // exclusive
    LOAD_KV(kA, vA, 0);
    int kb = 0;
    for (; kb + 64 <= kend; kb += 64) {
      LOAD_KV(kB, vB, kb + 32);
      COMPUTE_TILE(kA, vA, kb, false);
      if (kb + 64 < kend) LOAD_KV(kA, vA, kb + 64);
      COMPUTE_TILE(kB, vB, kb + 32, false);
    }
    if (kb < kend) {
      COMPUTE_TILE(kA, vA, kb, false);
    }
  }
#undef LOAD_KV
#undef COMPUTE_TILE

  // ---- split-KV merge ----
  if (half) {
    float* dst = Ms[w & 1][l];
#pragma unroll
    for (int db = 0; db < 4; db++)
#pragma unroll
      for (int r = 0; r < 16; r++) dst[db * 16 + r] = oacc[db][r];
    dst[64] = m;
    dst[65] = lsum;
  }
  __syncthreads();
  if (!half) {
    const float* src = Ms[w & 1][l];
    const float mB = src[64], lB = src[65];
    const float mS = fmaxf(m, mB);
    float fa = __builtin_amdgcn_exp2f(m - mS);
    float fb = __builtin_amdgcn_exp2f(mB - mS);
    const float inv = 1.0f / (lsum * fa + lB * fb);
    fa *= inv;
    fb *= inv;
    // write O[q][h*128 + d], d = db*32 + 8*rg + 4*hiP + (r&3)
    __hip_bfloat16* orow = O + (size_t)qg * (NQH * DH) + h * DH;
#pragma unroll
    for (int db = 0; db < 4; db++)
#pragma unroll
      for (int rg = 0; rg < 4; rg++) {
        ushort4 u;
        u.x = f2bf_bits(oacc[db][rg * 4 + 0] * fa + src[db * 16 + rg * 4 + 0] * fb);
        u.y = f2bf_bits(oacc[db][rg * 4 + 1] * fa + src[db * 16 + rg * 4 + 1] * fb);
        u.z = f2bf_bits(oacc[db][rg * 4 + 2] * fa + src[db * 16 + rg * 4 + 2] * fb);
        u.w = f2bf_bits(oacc[db][rg * 4 + 3] * fa + src[db * 16 + rg * 4 + 3] * fb);
        *reinterpret_cast<ushort4*>(orow + db * 32 + 8 * rg + 4 * hiP) = u;
      }
  }
}

// ---------------------------------------------------------------------------
extern "C" void kernel_launch(void* const* d_in, const int* in_sizes, int n_in,
                              void* d_out, int out_size, void* d_ws,
                              size_t ws_size, hipStream_t stream) {
  const float* hs = (const float*)d_in[0];
  const int* pos = (const int*)d_in[1];
  const float* wqkv = (const float*)d_in[2];
  const float* wo = (const float*)d_in[3];
  float* out = (float*)d_out;

  char* ws = (char*)d_ws;
  __hip_bfloat16* Xb      = (__hip_bfloat16*)(ws);                // 16 MB
  __hip_bfloat16* Wqkvb   = (__hip_bfloat16*)(ws + 16777216);     // 48 MB
  __hip_bfloat16* Wob     = (__hip_bfloat16*)(ws + 67108864);     // 32 MB
  __hip_bfloat16* QKV     = (__hip_bfloat16*)(ws + 100663296);    // 24 MB
  __hip_bfloat16* AttnOut = (__hip_bfloat16*)(ws + 125829120);    // 16 MB
  __hip_bfloat16* Vt      = (__hip_bfloat16*)(ws + 142606336);    // 4 MB

  cvt_f32_bf16<<<2048, 256, 0, stream>>>(hs, Xb, S_SEQ * HID);
  cvt_f32_bf16<<<2048, 256, 0, stream>>>(wqkv, Wqkvb, QKV_LD * HID);
  cvt_f32_bf16<<<2048, 256, 0, stream>>>(wo, Wob, HID * HID);

  gemm_bt_kernel<true><<<dim3(QKV_LD / 128, S_SEQ / 128), 256, 0, stream>>>(
      Xb, Wqkvb, QKV, S_SEQ, QKV_LD, HID);

  rope_kernel<<<(S_SEQ * 40 * 64) / 256, 256, 0, stream>>>(QKV, pos);
  vtrans_kernel<<<(NKVH * DH * S_SEQ) / 256, 256, 0, stream>>>(QKV, Vt);

  attn_kernel<<<1024, 256, 0, stream>>>(QKV, Vt, AttnOut);

  gemm_bt_kernel<false><<<dim3(HID / 128, S_SEQ / 128), 256, 0, stream>>>(
      AttnOut, Wob, out, S_SEQ, HID, HID);
}

// Round 8
// 464.372 us; speedup vs baseline: 1.8594x; 1.8594x over previous
//
#include <hip/hip_runtime.h>
#include <hip/hip_bf16.h>
#include <cstdint>

#define S_SEQ   2048
#define HID     4096
#define NQH     32
#define NKVH    8
#define DH      128
#define QKV_LD  6144      // (32+16)*128
#define SCALE_F 0.08838834764831845f
// softmax in log2 domain: s' = s * SCALE * log2(e)
#define C2F (0.08838834764831845f * 1.4426950408889634f)

using f32x4  = __attribute__((ext_vector_type(4))) float;
using f32x16 = __attribute__((ext_vector_type(16))) float;
using bf16x8 = __attribute__((ext_vector_type(8))) __bf16;
using u32x2  = __attribute__((ext_vector_type(2))) unsigned;

#define GLOAD_LDS16(gp, lp)                                                   \
  __builtin_amdgcn_global_load_lds(                                           \
      (__attribute__((address_space(1))) const void*)(gp),                    \
      (__attribute__((address_space(3))) void*)(lp), 16, 0, 0)

__device__ __forceinline__ unsigned short f2bf_bits(float f) {
  __hip_bfloat16 b = __float2bfloat16(f);
  return __builtin_bit_cast(unsigned short, b);
}

// permlane32_swap: X[32..63] <-> Y[0..31].
__device__ __forceinline__ void plswap(unsigned& x, unsigned& y) {
  u32x2 r = __builtin_amdgcn_permlane32_swap(x, y, false, false);
  x = r[0];
  y = r[1];
}
// value of the partner lane (l ^ 32)
__device__ __forceinline__ float xhalf(float v, int hiP) {
  unsigned u = __builtin_bit_cast(unsigned, v);
  u32x2 r = __builtin_amdgcn_permlane32_swap(u, u, false, false);
  return __builtin_bit_cast(float, hiP ? r[0] : r[1]);
}

// ---------------------------------------------------------------------------
// f32 -> bf16 conversion (vectorized, grid-stride)
// ---------------------------------------------------------------------------
__global__ void cvt_f32_bf16(const float* __restrict__ in,
                             __hip_bfloat16* __restrict__ out, int n) {
  int i = blockIdx.x * blockDim.x + threadIdx.x;
  int stride = gridDim.x * blockDim.x;
  for (int e = i * 4; e < n; e += stride * 4) {
    float4 v = *(const float4*)(in + e);
    ushort4 u;
    u.x = f2bf_bits(v.x); u.y = f2bf_bits(v.y);
    u.z = f2bf_bits(v.z); u.w = f2bf_bits(v.w);
    *reinterpret_cast<ushort4*>(reinterpret_cast<unsigned short*>(out) + e) = u;
  }
}

// ---------------------------------------------------------------------------
// GEMM: C[M,N] = A[M,K] * B[N,K]^T   (both bf16, B^T layout)  (m97 structure)
// + bijective XCD swizzle on the flattened block id (grids are %8 == 0).
// ---------------------------------------------------------------------------
template <bool OUT_BF16>
__global__ __launch_bounds__(256) void gemm_bt_kernel(
    const __hip_bfloat16* __restrict__ A, const __hip_bfloat16* __restrict__ B,
    void* __restrict__ Cv, int M, int N, int K) {
  __shared__ __hip_bfloat16 sA[128 * 32];
  __shared__ __hip_bfloat16 sB[128 * 32];
  const int tid = threadIdx.x;
  const int w = tid >> 6, l = tid & 63;
  const int wr = w >> 1, wc = w & 1;
  const int lr = l & 15, lk = (l >> 4) << 3;

  const int nbx = gridDim.x;
  const int nwg = nbx * gridDim.y;
  int wgid = blockIdx.y * nbx + blockIdx.x;
  wgid = (wgid & 7) * (nwg >> 3) + (wgid >> 3);  // XCD chunking
  const int brow = (wgid / nbx) * 128;
  const int bcol = (wgid % nbx) * 128;

  f32x4 acc[4][4];
#pragma unroll
  for (int m = 0; m < 4; m++)
#pragma unroll
    for (int n = 0; n < 4; n++) acc[m][n] = (f32x4){0.f, 0.f, 0.f, 0.f};

  const int r0 = tid >> 2;
  const int c0 = (tid & 3) << 3;
  const __hip_bfloat16* Ag = A + (size_t)(brow + r0) * K + c0;
  const __hip_bfloat16* Bg = B + (size_t)(bcol + r0) * K + c0;

  for (int k0 = 0; k0 < K; k0 += 32) {
    GLOAD_LDS16(Ag + k0,                  sA + tid * 8);
    GLOAD_LDS16(Ag + k0 + (size_t)64 * K, sA + 2048 + tid * 8);
    GLOAD_LDS16(Bg + k0,                  sB + tid * 8);
    GLOAD_LDS16(Bg + k0 + (size_t)64 * K, sB + 2048 + tid * 8);
    __syncthreads();

    bf16x8 af[4], bfr[4];
#pragma unroll
    for (int m = 0; m < 4; m++)
      af[m] = *(const bf16x8*)&sA[(wr * 64 + m * 16 + lr) * 32 + lk];
#pragma unroll
    for (int n = 0; n < 4; n++)
      bfr[n] = *(const bf16x8*)&sB[(wc * 64 + n * 16 + lr) * 32 + lk];
#pragma unroll
    for (int m = 0; m < 4; m++)
#pragma unroll
      for (int n = 0; n < 4; n++)
        acc[m][n] = __builtin_amdgcn_mfma_f32_16x16x32_bf16(af[m], bfr[n],
                                                            acc[m][n], 0, 0, 0);
    __syncthreads();
  }

  const int jr = (l >> 4) << 2;
  if (OUT_BF16) {
    __hip_bfloat16* C = (__hip_bfloat16*)Cv;
#pragma unroll
    for (int m = 0; m < 4; m++)
#pragma unroll
      for (int n = 0; n < 4; n++)
#pragma unroll
        for (int j = 0; j < 4; j++) {
          size_t row = brow + wr * 64 + m * 16 + jr + j;
          size_t col = bcol + wc * 64 + n * 16 + lr;
          C[row * N + col] = __float2bfloat16(acc[m][n][j]);
        }
  } else {
    float* C = (float*)Cv;
#pragma unroll
    for (int m = 0; m < 4; m++)
#pragma unroll
      for (int n = 0; n < 4; n++)
#pragma unroll
        for (int j = 0; j < 4; j++) {
          size_t row = brow + wr * 64 + m * 16 + jr + j;
          size_t col = bcol + wc * 64 + n * 16 + lr;
          C[row * N + col] = acc[m][n][j];
        }
  }
}

// ---------------------------------------------------------------------------
// RoPE (neox) in-place on Q (heads 0..31) and K (heads 32..39) of QKV.
// ---------------------------------------------------------------------------
__global__ void rope_kernel(__hip_bfloat16* __restrict__ QKV,
                            const int* __restrict__ pos) {
  int idx = blockIdx.x * blockDim.x + threadIdx.x;  // S*40*64 total
  int d = idx & 63;
  int head = (idx >> 6) % 40;
  int s = idx / (64 * 40);
  float p = (float)pos[s];
  float inv = exp2f(-(float)d * 0.2076205059304297f);
  float fr = p * inv;
  float sn, cs;
  sincosf(fr, &sn, &cs);
  size_t base = (size_t)s * QKV_LD + head * 128 + d;
  float x1 = __bfloat162float(QKV[base]);
  float x2 = __bfloat162float(QKV[base + 64]);
  QKV[base]      = __float2bfloat16(x1 * cs - x2 * sn);
  QKV[base + 64] = __float2bfloat16(x2 * cs + x1 * sn);
}

// ---------------------------------------------------------------------------
// V transpose: Vt[kvh][d][s] = QKV[s][5120 + kvh*128 + d]
// ---------------------------------------------------------------------------
__global__ void vtrans_kernel(const __hip_bfloat16* __restrict__ QKV,
                              __hip_bfloat16* __restrict__ Vt) {
  int idx = blockIdx.x * blockDim.x + threadIdx.x;  // 8*128*2048
  int s = idx & 2047;
  int d = (idx >> 11) & 127;
  int kh = idx >> 18;
  Vt[idx] = QKV[(size_t)s * QKV_LD + 5120 + kh * 128 + d];
}

// ---------------------------------------------------------------------------
// Causal GQA flash attention, v7: swapped-QK 32x32 zero-staging tiles
// + split-KV x2, allocator-friendly (no reg double-buffer, no hard VGPR cap).
//
// Block = (kvh, head-pair, qt): warps 0,1 = heads hp*2+{0,1}, kv tiles
// [0, nt/2); warps 2,3 = same heads, kv tiles [nt/2, nt) incl. diagonal.
// Half-1 warps publish (oacc, m, lsum) to LDS; one barrier; half-0 warps
// merge and write O. Grid 1024 = 8 kvh x 2 hp x 64 qt (longest-first).
//
// mfma_f32_32x32x16_bf16 layouts:
//   A-frag: lane l holds A[row = l&31][k = (l>>5)*8 + j], j=0..7
//   B-frag: lane l holds B[k = (l>>5)*8 + j][col = l&31]
//   C/D:    lane l holds D[row = (r&3)+8*(r>>2)+4*(l>>5)][col = l&31], r=0..15
// ---------------------------------------------------------------------------
__global__ __launch_bounds__(256, 2) void attn_kernel(
    const __hip_bfloat16* __restrict__ QKV,
    const __hip_bfloat16* __restrict__ Vt, __hip_bfloat16* __restrict__ O) {
  __shared__ float Ms[2][64][67];  // [head-slot][lane][64 oacc + m + lsum]
  const int tid = threadIdx.x;
  const int w = tid >> 6, l = tid & 63;
  const int l31 = l & 31;
  const int hiP = l >> 5;
  const int bid = blockIdx.x;
  const int kvh = bid & 7;                 // XCD-resident kv head
  const int hp = (bid >> 3) & 1;           // head pair within kv group
  const int qt = 63 - (bid >> 4);          // longest blocks dispatched first
  const int half = w >> 1;                 // kv-range half
  const int h = kvh * 4 + hp * 2 + (w & 1);
  const int qwb = qt * 32;                 // q base row
  const int qg = qwb + l31;                // this lane's q row

  const __hip_bfloat16* Qp = QKV + (size_t)h * DH;
  const __hip_bfloat16* Kp = QKV + 4096 + (size_t)kvh * DH;
  const __hip_bfloat16* Vp = Vt + (size_t)kvh * (DH * S_SEQ);

  // Q B-frags (held whole kernel): qf[ks] = Q[q=l31][ks*16 + hiP*8 .. +8]
  bf16x8 qf[8];
  {
    const __hip_bfloat16* qrow = Qp + (size_t)(qwb + l31) * QKV_LD + hiP * 8;
#pragma unroll
    for (int ks = 0; ks < 8; ks++) qf[ks] = *(const bf16x8*)(qrow + ks * 16);
  }

  f32x16 oacc[4];
#pragma unroll
  for (int db = 0; db < 4; db++)
#pragma unroll
    for (int r = 0; r < 16; r++) oacc[db][r] = 0.f;
  float m = -1e30f, lsum = 0.f;

// K loads -> QK MFMAs -> V loads (latency hidden under softmax) -> softmax
// -> P pack/exchange -> PV MFMAs.  kf dead before vf peaks: low reg pressure.
#define COMPUTE_TILE(KB, MASKED)                                               \
  {                                                                            \
    const int kb_ = (KB);                                                      \
    f32x16 sacc;                                                               \
    _Pragma("unroll") for (int r = 0; r < 16; r++) sacc[r] = 0.f;              \
    {                                                                          \
      bf16x8 kf[8];                                                            \
      const __hip_bfloat16* krow =                                             \
          Kp + (size_t)(kb_ + l31) * QKV_LD + hiP * 8;                         \
      _Pragma("unroll") for (int ks = 0; ks < 8; ks++) kf[ks] =                \
          *(const bf16x8*)(krow + ks * 16);                                    \
      _Pragma("unroll") for (int ks = 0; ks < 8; ks++) sacc =                  \
          __builtin_amdgcn_mfma_f32_32x32x16_bf16(kf[ks], qf[ks], sacc, 0, 0,  \
                                                  0);                          \
    }                                                                          \
    bf16x8 vf[4][2];                                                           \
    _Pragma("unroll") for (int db = 0; db < 4; db++)                           \
        _Pragma("unroll") for (int k2 = 0; k2 < 2; k2++) vf[db][k2] =          \
        *(const bf16x8*)(Vp + (size_t)(db * 32 + l31) * S_SEQ + kb_ +          \
                         k2 * 16 + hiP * 8);                                   \
    float s[16];                                                               \
    _Pragma("unroll") for (int r = 0; r < 16; r++) s[r] = sacc[r] * C2F;       \
    if (MASKED) {                                                              \
      _Pragma("unroll") for (int r = 0; r < 16; r++) {                         \
        const int kvg = kb_ + (r & 3) + 8 * (r >> 2) + 4 * hiP;                \
        s[r] = (kvg <= qg) ? s[r] : -1e30f;                                    \
      }                                                                        \
    }                                                                          \
    float m0 = fmaxf(fmaxf(s[0], s[1]), fmaxf(s[2], s[3]));                    \
    float m1 = fmaxf(fmaxf(s[4], s[5]), fmaxf(s[6], s[7]));                    \
    float m2 = fmaxf(fmaxf(s[8], s[9]), fmaxf(s[10], s[11]));                  \
    float m3 = fmaxf(fmaxf(s[12], s[13]), fmaxf(s[14], s[15]));                \
    float rmax = fmaxf(fmaxf(m0, m1), fmaxf(m2, m3));                          \
    rmax = fmaxf(rmax, xhalf(rmax, hiP));                                      \
    if (__any(rmax - m > 8.0f)) {                                              \
      float mn = fmaxf(m, rmax);                                               \
      float sc = __builtin_amdgcn_exp2f(m - mn);                               \
      lsum *= sc;                                                              \
      _Pragma("unroll") for (int db = 0; db < 4; db++)                         \
          _Pragma("unroll") for (int r = 0; r < 16; r++) oacc[db][r] *= sc;    \
      m = mn;                                                                  \
    }                                                                          \
    float p[16];                                                               \
    _Pragma("unroll") for (int r = 0; r < 16; r++) p[r] =                      \
        __builtin_amdgcn_exp2f(s[r] - m);                                      \
    float rs = ((p[0] + p[1]) + (p[2] + p[3])) +                               \
               ((p[4] + p[5]) + (p[6] + p[7])) +                               \
               ((p[8] + p[9]) + (p[10] + p[11])) +                             \
               ((p[12] + p[13]) + (p[14] + p[15]));                            \
    lsum += rs + xhalf(rs, hiP);                                               \
    unsigned Wp[8];                                                            \
    _Pragma("unroll") for (int i = 0; i < 8; i++) Wp[i] =                      \
        (unsigned)f2bf_bits(p[2 * i]) |                                        \
        ((unsigned)f2bf_bits(p[2 * i + 1]) << 16);                             \
    unsigned s0x = Wp[0], s0y = Wp[2];                                         \
    unsigned s1x = Wp[1], s1y = Wp[3];                                         \
    unsigned s2x = Wp[4], s2y = Wp[6];                                         \
    unsigned s3x = Wp[5], s3y = Wp[7];                                         \
    plswap(s0x, s0y);                                                          \
    plswap(s1x, s1y);                                                          \
    plswap(s2x, s2y);                                                          \
    plswap(s3x, s3y);                                                          \
    int4 f0, f1;                                                               \
    f0.x = (int)s0x; f0.y = (int)s1x; f0.z = (int)s0y; f0.w = (int)s1y;        \
    f1.x = (int)s2x; f1.y = (int)s3x; f1.z = (int)s2y; f1.w = (int)s3y;        \
    bf16x8 pfrag[2];                                                           \
    pfrag[0] = __builtin_bit_cast(bf16x8, f0);                                 \
    pfrag[1] = __builtin_bit_cast(bf16x8, f1);                                 \
    _Pragma("unroll") for (int db = 0; db < 4; db++)                           \
        _Pragma("unroll") for (int k2 = 0; k2 < 2; k2++) oacc[db] =            \
        __builtin_amdgcn_mfma_f32_32x32x16_bf16(vf[db][k2], pfrag[k2],         \
                                                oacc[db], 0, 0, 0);            \
  }

  const int nt = qt + 1;
  const int nt0 = nt >> 1;  // tiles in half 0 (may be 0)

  if (half) {
    for (int kb = nt0 * 32; kb < qwb; kb += 32) COMPUTE_TILE(kb, false);
    COMPUTE_TILE(qwb, true);
  } else {
    const int kend = nt0 * 32;
    for (int kb = 0; kb < kend; kb += 32) COMPUTE_TILE(kb, false);
  }
#undef COMPUTE_TILE

  // ---- split-KV merge ----
  if (half) {
    float* dst = Ms[w & 1][l];
#pragma unroll
    for (int db = 0; db < 4; db++)
#pragma unroll
      for (int r = 0; r < 16; r++) dst[db * 16 + r] = oacc[db][r];
    dst[64] = m;
    dst[65] = lsum;
  }
  __syncthreads();
  if (!half) {
    const float* src = Ms[w & 1][l];
    const float mB = src[64], lB = src[65];
    const float mS = fmaxf(m, mB);
    float fa = __builtin_amdgcn_exp2f(m - mS);
    float fb = __builtin_amdgcn_exp2f(mB - mS);
    const float inv = 1.0f / (lsum * fa + lB * fb);
    fa *= inv;
    fb *= inv;
    // write O[q][h*128 + d], d = db*32 + 8*rg + 4*hiP + (r&3)
    __hip_bfloat16* orow = O + (size_t)qg * (NQH * DH) + h * DH;
#pragma unroll
    for (int db = 0; db < 4; db++)
#pragma unroll
      for (int rg = 0; rg < 4; rg++) {
        ushort4 u;
        u.x = f2bf_bits(oacc[db][rg * 4 + 0] * fa + src[db * 16 + rg * 4 + 0] * fb);
        u.y = f2bf_bits(oacc[db][rg * 4 + 1] * fa + src[db * 16 + rg * 4 + 1] * fb);
        u.z = f2bf_bits(oacc[db][rg * 4 + 2] * fa + src[db * 16 + rg * 4 + 2] * fb);
        u.w = f2bf_bits(oacc[db][rg * 4 + 3] * fa + src[db * 16 + rg * 4 + 3] * fb);
        *reinterpret_cast<ushort4*>(orow + db * 32 + 8 * rg + 4 * hiP) = u;
      }
  }
}

// ---------------------------------------------------------------------------
extern "C" void kernel_launch(void* const* d_in, const int* in_sizes, int n_in,
                              void* d_out, int out_size, void* d_ws,
                              size_t ws_size, hipStream_t stream) {
  const float* hs = (const float*)d_in[0];
  const int* pos = (const int*)d_in[1];
  const float* wqkv = (const float*)d_in[2];
  const float* wo = (const float*)d_in[3];
  float* out = (float*)d_out;

  char* ws = (char*)d_ws;
  __hip_bfloat16* Xb      = (__hip_bfloat16*)(ws);                // 16 MB
  __hip_bfloat16* Wqkvb   = (__hip_bfloat16*)(ws + 16777216);     // 48 MB
  __hip_bfloat16* Wob     = (__hip_bfloat16*)(ws + 67108864);     // 32 MB
  __hip_bfloat16* QKV     = (__hip_bfloat16*)(ws + 100663296);    // 24 MB
  __hip_bfloat16* AttnOut = (__hip_bfloat16*)(ws + 125829120);    // 16 MB
  __hip_bfloat16* Vt      = (__hip_bfloat16*)(ws + 142606336);    // 4 MB

  cvt_f32_bf16<<<2048, 256, 0, stream>>>(hs, Xb, S_SEQ * HID);
  cvt_f32_bf16<<<2048, 256, 0, stream>>>(wqkv, Wqkvb, QKV_LD * HID);
  cvt_f32_bf16<<<2048, 256, 0, stream>>>(wo, Wob, HID * HID);

  gemm_bt_kernel<true><<<dim3(QKV_LD / 128, S_SEQ / 128), 256, 0, stream>>>(
      Xb, Wqkvb, QKV, S_SEQ, QKV_LD, HID);

  rope_kernel<<<(S_SEQ * 40 * 64) / 256, 256, 0, stream>>>(QKV, pos);
  vtrans_kernel<<<(NKVH * DH * S_SEQ) / 256, 256, 0, stream>>>(QKV, Vt);

  attn_kernel<<<1024, 256, 0, stream>>>(QKV, Vt, AttnOut);

  gemm_bt_kernel<false><<<dim3(HID / 128, S_SEQ / 128), 256, 0, stream>>>(
      AttnOut, Wob, out, S_SEQ, HID, HID);
}

// Round 9
// 452.683 us; speedup vs baseline: 1.9074x; 1.0258x over previous
//
#include <hip/hip_runtime.h>
#include <hip/hip_bf16.h>
#include <cstdint>

#define S_SEQ   2048
#define HID     4096
#define NQH     32
#define NKVH    8
#define DH      128
#define QKV_LD  6144      // (32+16)*128
#define SCALE_F 0.08838834764831845f
// softmax in log2 domain: s' = s * SCALE * log2(e)
#define C2F (0.08838834764831845f * 1.4426950408889634f)

using f32x4  = __attribute__((ext_vector_type(4))) float;
using f32x16 = __attribute__((ext_vector_type(16))) float;
using bf16x8 = __attribute__((ext_vector_type(8))) __bf16;
using u32x2  = __attribute__((ext_vector_type(2))) unsigned;

#define GLOAD_LDS16(gp, lp)                                                   \
  __builtin_amdgcn_global_load_lds(                                           \
      (__attribute__((address_space(1))) const void*)(gp),                    \
      (__attribute__((address_space(3))) void*)(lp), 16, 0, 0)

__device__ __forceinline__ unsigned short f2bf_bits(float f) {
  __hip_bfloat16 b = __float2bfloat16(f);
  return __builtin_bit_cast(unsigned short, b);
}

// permlane32_swap: X[32..63] <-> Y[0..31].
__device__ __forceinline__ void plswap(unsigned& x, unsigned& y) {
  u32x2 r = __builtin_amdgcn_permlane32_swap(x, y, false, false);
  x = r[0];
  y = r[1];
}
// value of the partner lane (l ^ 32)
__device__ __forceinline__ float xhalf(float v, int hiP) {
  unsigned u = __builtin_bit_cast(unsigned, v);
  u32x2 r = __builtin_amdgcn_permlane32_swap(u, u, false, false);
  return __builtin_bit_cast(float, hiP ? r[0] : r[1]);
}

// ---------------------------------------------------------------------------
// f32 -> bf16 conversion (vectorized, grid-stride)
// ---------------------------------------------------------------------------
__global__ void cvt_f32_bf16(const float* __restrict__ in,
                             __hip_bfloat16* __restrict__ out, int n) {
  int i = blockIdx.x * blockDim.x + threadIdx.x;
  int stride = gridDim.x * blockDim.x;
  for (int e = i * 4; e < n; e += stride * 4) {
    float4 v = *(const float4*)(in + e);
    ushort4 u;
    u.x = f2bf_bits(v.x); u.y = f2bf_bits(v.y);
    u.z = f2bf_bits(v.z); u.w = f2bf_bits(v.w);
    *reinterpret_cast<ushort4*>(reinterpret_cast<unsigned short*>(out) + e) = u;
  }
}

// ---------------------------------------------------------------------------
// GEMM: C[M,N] = A[M,K] * B[N,K]^T   (both bf16, B^T layout)
// 128x128 tile, BK=64, 4 waves, XOR-swizzled LDS (slot ^= row&7):
//  - staging: global_load_lds width=16, linear LDS dest, inverse-swizzled
//    global source col8 = (l&7)^((l>>3)&7)  [rule #21: both-sides-or-neither]
//  - ds_read: slot = (ks*4 + l>>4) ^ (lr&7)  -> 2-way max (free)
//  - bijective XCD swizzle on flattened wgid (grids are %8 == 0)
// ---------------------------------------------------------------------------
template <bool OUT_BF16>
__global__ __launch_bounds__(256) void gemm_bt_kernel(
    const __hip_bfloat16* __restrict__ A, const __hip_bfloat16* __restrict__ B,
    void* __restrict__ Cv, int M, int N, int K) {
  __shared__ __hip_bfloat16 sA[128 * 64];
  __shared__ __hip_bfloat16 sB[128 * 64];
  const int tid = threadIdx.x;
  const int w = tid >> 6, l = tid & 63;
  const int wr = w >> 1, wc = w & 1;
  const int lr = l & 15, g = l >> 4;

  const int nbx = gridDim.x;
  const int nwg = nbx * gridDim.y;
  int wgid = blockIdx.y * nbx + blockIdx.x;
  wgid = (wgid & 7) * (nwg >> 3) + (wgid >> 3);  // XCD chunking
  const int brow = (wgid / nbx) * 128;
  const int bcol = (wgid % nbx) * 128;

  f32x4 acc[4][4];
#pragma unroll
  for (int m = 0; m < 4; m++)
#pragma unroll
    for (int n = 0; n < 4; n++) acc[m][n] = (f32x4){0.f, 0.f, 0.f, 0.f};

  // staging geometry: wave w stages rows [w*32, w*32+32); load i covers 8 rows
  const int r_base = w * 32 + (l >> 3);
  const int scol = (((l & 7) ^ ((l >> 3) & 7)) << 3);  // inverse-swizzled src
  const __hip_bfloat16* Ag = A + (size_t)(brow + r_base) * K + scol;
  const __hip_bfloat16* Bg = B + (size_t)(bcol + r_base) * K + scol;
  const int ldsoff = w * 2048 + l * 8;  // elements; + i*512

  // swizzled ds_read slot per (ks): ((ks*4 + g) ^ (lr&7)) * 8
  const int rsw = (lr & 7);

  for (int k0 = 0; k0 < K; k0 += 64) {
#pragma unroll
    for (int i = 0; i < 4; i++) {
      GLOAD_LDS16(Ag + k0 + (size_t)(i * 8) * K, sA + ldsoff + i * 512);
      GLOAD_LDS16(Bg + k0 + (size_t)(i * 8) * K, sB + ldsoff + i * 512);
    }
    __syncthreads();

    bf16x8 af[2][4], bfr[2][4];
#pragma unroll
    for (int ks = 0; ks < 2; ks++) {
      const int slot = ((ks * 4 + g) ^ rsw) * 8;
#pragma unroll
      for (int m = 0; m < 4; m++)
        af[ks][m] = *(const bf16x8*)&sA[(wr * 64 + m * 16 + lr) * 64 + slot];
#pragma unroll
      for (int n = 0; n < 4; n++)
        bfr[ks][n] = *(const bf16x8*)&sB[(wc * 64 + n * 16 + lr) * 64 + slot];
    }
#pragma unroll
    for (int ks = 0; ks < 2; ks++)
#pragma unroll
      for (int m = 0; m < 4; m++)
#pragma unroll
        for (int n = 0; n < 4; n++)
          acc[m][n] = __builtin_amdgcn_mfma_f32_16x16x32_bf16(
              af[ks][m], bfr[ks][n], acc[m][n], 0, 0, 0);
    __syncthreads();
  }

  const int jr = (l >> 4) << 2;
  if (OUT_BF16) {
    __hip_bfloat16* C = (__hip_bfloat16*)Cv;
#pragma unroll
    for (int m = 0; m < 4; m++)
#pragma unroll
      for (int n = 0; n < 4; n++)
#pragma unroll
        for (int j = 0; j < 4; j++) {
          size_t row = brow + wr * 64 + m * 16 + jr + j;
          size_t col = bcol + wc * 64 + n * 16 + lr;
          C[row * N + col] = __float2bfloat16(acc[m][n][j]);
        }
  } else {
    float* C = (float*)Cv;
#pragma unroll
    for (int m = 0; m < 4; m++)
#pragma unroll
      for (int n = 0; n < 4; n++)
#pragma unroll
        for (int j = 0; j < 4; j++) {
          size_t row = brow + wr * 64 + m * 16 + jr + j;
          size_t col = bcol + wc * 64 + n * 16 + lr;
          C[row * N + col] = acc[m][n][j];
        }
  }
}

// ---------------------------------------------------------------------------
// RoPE (neox) in-place on Q (heads 0..31) and K (heads 32..39) of QKV.
// ---------------------------------------------------------------------------
__global__ void rope_kernel(__hip_bfloat16* __restrict__ QKV,
                            const int* __restrict__ pos) {
  int idx = blockIdx.x * blockDim.x + threadIdx.x;  // S*40*64 total
  int d = idx & 63;
  int head = (idx >> 6) % 40;
  int s = idx / (64 * 40);
  float p = (float)pos[s];
  float inv = exp2f(-(float)d * 0.2076205059304297f);
  float fr = p * inv;
  float sn, cs;
  sincosf(fr, &sn, &cs);
  size_t base = (size_t)s * QKV_LD + head * 128 + d;
  float x1 = __bfloat162float(QKV[base]);
  float x2 = __bfloat162float(QKV[base + 64]);
  QKV[base]      = __float2bfloat16(x1 * cs - x2 * sn);
  QKV[base + 64] = __float2bfloat16(x2 * cs + x1 * sn);
}

// ---------------------------------------------------------------------------
// V transpose: Vt[kvh][d][s] = QKV[s][5120 + kvh*128 + d]
// ---------------------------------------------------------------------------
__global__ void vtrans_kernel(const __hip_bfloat16* __restrict__ QKV,
                              __hip_bfloat16* __restrict__ Vt) {
  int idx = blockIdx.x * blockDim.x + threadIdx.x;  // 8*128*2048
  int s = idx & 2047;
  int d = (idx >> 11) & 127;
  int kh = idx >> 18;
  Vt[idx] = QKV[(size_t)s * QKV_LD + 5120 + kh * 128 + d];
}

// ---------------------------------------------------------------------------
// Causal GQA flash attention, v7 (unchanged from R8): swapped-QK 32x32
// zero-staging tiles + split-KV x2.
// ---------------------------------------------------------------------------
__global__ __launch_bounds__(256, 2) void attn_kernel(
    const __hip_bfloat16* __restrict__ QKV,
    const __hip_bfloat16* __restrict__ Vt, __hip_bfloat16* __restrict__ O) {
  __shared__ float Ms[2][64][67];  // [head-slot][lane][64 oacc + m + lsum]
  const int tid = threadIdx.x;
  const int w = tid >> 6, l = tid & 63;
  const int l31 = l & 31;
  const int hiP = l >> 5;
  const int bid = blockIdx.x;
  const int kvh = bid & 7;                 // XCD-resident kv head
  const int hp = (bid >> 3) & 1;           // head pair within kv group
  const int qt = 63 - (bid >> 4);          // longest blocks dispatched first
  const int half = w >> 1;                 // kv-range half
  const int h = kvh * 4 + hp * 2 + (w & 1);
  const int qwb = qt * 32;                 // q base row
  const int qg = qwb + l31;                // this lane's q row

  const __hip_bfloat16* Qp = QKV + (size_t)h * DH;
  const __hip_bfloat16* Kp = QKV + 4096 + (size_t)kvh * DH;
  const __hip_bfloat16* Vp = Vt + (size_t)kvh * (DH * S_SEQ);

  // Q B-frags (held whole kernel): qf[ks] = Q[q=l31][ks*16 + hiP*8 .. +8]
  bf16x8 qf[8];
  {
    const __hip_bfloat16* qrow = Qp + (size_t)(qwb + l31) * QKV_LD + hiP * 8;
#pragma unroll
    for (int ks = 0; ks < 8; ks++) qf[ks] = *(const bf16x8*)(qrow + ks * 16);
  }

  f32x16 oacc[4];
#pragma unroll
  for (int db = 0; db < 4; db++)
#pragma unroll
    for (int r = 0; r < 16; r++) oacc[db][r] = 0.f;
  float m = -1e30f, lsum = 0.f;

#define COMPUTE_TILE(KB, MASKED)                                               \
  {                                                                            \
    const int kb_ = (KB);                                                      \
    f32x16 sacc;                                                               \
    _Pragma("unroll") for (int r = 0; r < 16; r++) sacc[r] = 0.f;              \
    {                                                                          \
      bf16x8 kf[8];                                                            \
      const __hip_bfloat16* krow =                                             \
          Kp + (size_t)(kb_ + l31) * QKV_LD + hiP * 8;                         \
      _Pragma("unroll") for (int ks = 0; ks < 8; ks++) kf[ks] =                \
          *(const bf16x8*)(krow + ks * 16);                                    \
      _Pragma("unroll") for (int ks = 0; ks < 8; ks++) sacc =                  \
          __builtin_amdgcn_mfma_f32_32x32x16_bf16(kf[ks], qf[ks], sacc, 0, 0,  \
                                                  0);                          \
    }                                                                          \
    bf16x8 vf[4][2];                                                           \
    _Pragma("unroll") for (int db = 0; db < 4; db++)                           \
        _Pragma("unroll") for (int k2 = 0; k2 < 2; k2++) vf[db][k2] =          \
        *(const bf16x8*)(Vp + (size_t)(db * 32 + l31) * S_SEQ + kb_ +          \
                         k2 * 16 + hiP * 8);                                   \
    float s[16];                                                               \
    _Pragma("unroll") for (int r = 0; r < 16; r++) s[r] = sacc[r] * C2F;       \
    if (MASKED) {                                                              \
      _Pragma("unroll") for (int r = 0; r < 16; r++) {                         \
        const int kvg = kb_ + (r & 3) + 8 * (r >> 2) + 4 * hiP;                \
        s[r] = (kvg <= qg) ? s[r] : -1e30f;                                    \
      }                                                                        \
    }                                                                          \
    float m0 = fmaxf(fmaxf(s[0], s[1]), fmaxf(s[2], s[3]));                    \
    float m1 = fmaxf(fmaxf(s[4], s[5]), fmaxf(s[6], s[7]));                    \
    float m2 = fmaxf(fmaxf(s[8], s[9]), fmaxf(s[10], s[11]));                  \
    float m3 = fmaxf(fmaxf(s[12], s[13]), fmaxf(s[14], s[15]));                \
    float rmax = fmaxf(fmaxf(m0, m1), fmaxf(m2, m3));                          \
    rmax = fmaxf(rmax, xhalf(rmax, hiP));                                      \
    if (__any(rmax - m > 8.0f)) {                                              \
      float mn = fmaxf(m, rmax);                                               \
      float sc = __builtin_amdgcn_exp2f(m - mn);                               \
      lsum *= sc;                                                              \
      _Pragma("unroll") for (int db = 0; db < 4; db++)                         \
          _Pragma("unroll") for (int r = 0; r < 16; r++) oacc[db][r] *= sc;    \
      m = mn;                                                                  \
    }                                                                          \
    float p[16];                                                               \
    _Pragma("unroll") for (int r = 0; r < 16; r++) p[r] =                      \
        __builtin_amdgcn_exp2f(s[r] - m);                                      \
    float rs = ((p[0] + p[1]) + (p[2] + p[3])) +                               \
               ((p[4] + p[5]) + (p[6] + p[7])) +                               \
               ((p[8] + p[9]) + (p[10] + p[11])) +                             \
               ((p[12] + p[13]) + (p[14] + p[15]));                            \
    lsum += rs + xhalf(rs, hiP);                                               \
    unsigned Wp[8];                                                            \
    _Pragma("unroll") for (int i = 0; i < 8; i++) Wp[i] =                      \
        (unsigned)f2bf_bits(p[2 * i]) |                                        \
        ((unsigned)f2bf_bits(p[2 * i + 1]) << 16);                             \
    unsigned s0x = Wp[0], s0y = Wp[2];                                         \
    unsigned s1x = Wp[1], s1y = Wp[3];                                         \
    unsigned s2x = Wp[4], s2y = Wp[6];                                         \
    unsigned s3x = Wp[5], s3y = Wp[7];                                         \
    plswap(s0x, s0y);                                                          \
    plswap(s1x, s1y);                                                          \
    plswap(s2x, s2y);                                                          \
    plswap(s3x, s3y);                                                          \
    int4 f0, f1;                                                               \
    f0.x = (int)s0x; f0.y = (int)s1x; f0.z = (int)s0y; f0.w = (int)s1y;        \
    f1.x = (int)s2x; f1.y = (int)s3x; f1.z = (int)s2y; f1.w = (int)s3y;        \
    bf16x8 pfrag[2];                                                           \
    pfrag[0] = __builtin_bit_cast(bf16x8, f0);                                 \
    pfrag[1] = __builtin_bit_cast(bf16x8, f1);                                 \
    _Pragma("unroll") for (int db = 0; db < 4; db++)                           \
        _Pragma("unroll") for (int k2 = 0; k2 < 2; k2++) oacc[db] =            \
        __builtin_amdgcn_mfma_f32_32x32x16_bf16(vf[db][k2], pfrag[k2],         \
                                                oacc[db], 0, 0, 0);            \
  }

  const int nt = qt + 1;
  const int nt0 = nt >> 1;  // tiles in half 0 (may be 0)

  if (half) {
    for (int kb = nt0 * 32; kb < qwb; kb += 32) COMPUTE_TILE(kb, false);
    COMPUTE_TILE(qwb, true);
  } else {
    const int kend = nt0 * 32;
    for (int kb = 0; kb < kend; kb += 32) COMPUTE_TILE(kb, false);
  }
#undef COMPUTE_TILE

  // ---- split-KV merge ----
  if (half) {
    float* dst = Ms[w & 1][l];
#pragma unroll
    for (int db = 0; db < 4; db++)
#pragma unroll
      for (int r = 0; r < 16; r++) dst[db * 16 + r] = oacc[db][r];
    dst[64] = m;
    dst[65] = lsum;
  }
  __syncthreads();
  if (!half) {
    const float* src = Ms[w & 1][l];
    const float mB = src[64], lB = src[65];
    const float mS = fmaxf(m, mB);
    float fa = __builtin_amdgcn_exp2f(m - mS);
    float fb = __builtin_amdgcn_exp2f(mB - mS);
    const float inv = 1.0f / (lsum * fa + lB * fb);
    fa *= inv;
    fb *= inv;
    // write O[q][h*128 + d], d = db*32 + 8*rg + 4*hiP + (r&3)
    __hip_bfloat16* orow = O + (size_t)qg * (NQH * DH) + h * DH;
#pragma unroll
    for (int db = 0; db < 4; db++)
#pragma unroll
      for (int rg = 0; rg < 4; rg++) {
        ushort4 u;
        u.x = f2bf_bits(oacc[db][rg * 4 + 0] * fa + src[db * 16 + rg * 4 + 0] * fb);
        u.y = f2bf_bits(oacc[db][rg * 4 + 1] * fa + src[db * 16 + rg * 4 + 1] * fb);
        u.z = f2bf_bits(oacc[db][rg * 4 + 2] * fa + src[db * 16 + rg * 4 + 2] * fb);
        u.w = f2bf_bits(oacc[db][rg * 4 + 3] * fa + src[db * 16 + rg * 4 + 3] * fb);
        *reinterpret_cast<ushort4*>(orow + db * 32 + 8 * rg + 4 * hiP) = u;
      }
  }
}

// ---------------------------------------------------------------------------
extern "C" void kernel_launch(void* const* d_in, const int* in_sizes, int n_in,
                              void* d_out, int out_size, void* d_ws,
                              size_t ws_size, hipStream_t stream) {
  const float* hs = (const float*)d_in[0];
  const int* pos = (const int*)d_in[1];
  const float* wqkv = (const float*)d_in[2];
  const float* wo = (const float*)d_in[3];
  float* out = (float*)d_out;

  char* ws = (char*)d_ws;
  __hip_bfloat16* Xb      = (__hip_bfloat16*)(ws);                // 16 MB
  __hip_bfloat16* Wqkvb   = (__hip_bfloat16*)(ws + 16777216);     // 48 MB
  __hip_bfloat16* Wob     = (__hip_bfloat16*)(ws + 67108864);     // 32 MB
  __hip_bfloat16* QKV     = (__hip_bfloat16*)(ws + 100663296);    // 24 MB
  __hip_bfloat16* AttnOut = (__hip_bfloat16*)(ws + 125829120);    // 16 MB
  __hip_bfloat16* Vt      = (__hip_bfloat16*)(ws + 142606336);    // 4 MB

  cvt_f32_bf16<<<2048, 256, 0, stream>>>(hs, Xb, S_SEQ * HID);
  cvt_f32_bf16<<<2048, 256, 0, stream>>>(wqkv, Wqkvb, QKV_LD * HID);
  cvt_f32_bf16<<<2048, 256, 0, stream>>>(wo, Wob, HID * HID);

  gemm_bt_kernel<true><<<dim3(QKV_LD / 128, S_SEQ / 128), 256, 0, stream>>>(
      Xb, Wqkvb, QKV, S_SEQ, QKV_LD, HID);

  rope_kernel<<<(S_SEQ * 40 * 64) / 256, 256, 0, stream>>>(QKV, pos);
  vtrans_kernel<<<(NKVH * DH * S_SEQ) / 256, 256, 0, stream>>>(QKV, Vt);

  attn_kernel<<<1024, 256, 0, stream>>>(QKV, Vt, AttnOut);

  gemm_bt_kernel<false><<<dim3(HID / 128, S_SEQ / 128), 256, 0, stream>>>(
      AttnOut, Wob, out, S_SEQ, HID, HID);
}

// Round 10
// 414.101 us; speedup vs baseline: 2.0851x; 1.0932x over previous
//
#include <hip/hip_runtime.h>
#include <hip/hip_bf16.h>
#include <cstdint>

#define S_SEQ   2048
#define HID     4096
#define NQH     32
#define NKVH    8
#define DH      128
#define QKV_LD  6144      // (32+16)*128
#define SCALE_F 0.08838834764831845f
// softmax in log2 domain: s' = s * SCALE * log2(e)
#define C2F (0.08838834764831845f * 1.4426950408889634f)

using f32x4  = __attribute__((ext_vector_type(4))) float;
using f32x16 = __attribute__((ext_vector_type(16))) float;
using bf16x8 = __attribute__((ext_vector_type(8))) __bf16;
using u32x2  = __attribute__((ext_vector_type(2))) unsigned;

#define GLOAD_LDS16(gp, lp)                                                   \
  __builtin_amdgcn_global_load_lds(                                           \
      (__attribute__((address_space(1))) const void*)(gp),                    \
      (__attribute__((address_space(3))) void*)(lp), 16, 0, 0)

__device__ __forceinline__ unsigned short f2bf_bits(float f) {
  __hip_bfloat16 b = __float2bfloat16(f);
  return __builtin_bit_cast(unsigned short, b);
}

// permlane32_swap: X[32..63] <-> Y[0..31].
__device__ __forceinline__ void plswap(unsigned& x, unsigned& y) {
  u32x2 r = __builtin_amdgcn_permlane32_swap(x, y, false, false);
  x = r[0];
  y = r[1];
}
// value of the partner lane (l ^ 32)
__device__ __forceinline__ float xhalf(float v, int hiP) {
  unsigned u = __builtin_bit_cast(unsigned, v);
  u32x2 r = __builtin_amdgcn_permlane32_swap(u, u, false, false);
  return __builtin_bit_cast(float, hiP ? r[0] : r[1]);
}

// ---------------------------------------------------------------------------
// f32 -> bf16 conversion (vectorized, grid-stride)
// ---------------------------------------------------------------------------
__global__ void cvt_f32_bf16(const float* __restrict__ in,
                             __hip_bfloat16* __restrict__ out, int n) {
  int i = blockIdx.x * blockDim.x + threadIdx.x;
  int stride = gridDim.x * blockDim.x;
  for (int e = i * 4; e < n; e += stride * 4) {
    float4 v = *(const float4*)(in + e);
    ushort4 u;
    u.x = f2bf_bits(v.x); u.y = f2bf_bits(v.y);
    u.z = f2bf_bits(v.z); u.w = f2bf_bits(v.w);
    *reinterpret_cast<ushort4*>(reinterpret_cast<unsigned short*>(out) + e) = u;
  }
}

// ---------------------------------------------------------------------------
// GEMM: C[M,N] = A[M,K] * B[N,K]^T   (both bf16, B^T layout)
// R8 geometry (128x128, BK=32, 4 waves) upgraded to the recipe-form pipeline:
//  - LDS double-buffer, stage(t+1) issued BEFORE compute(t)
//  - raw s_barrier + counted vmcnt(4) (never 0 in the main loop)
//  - conflict-free LDS slot swizzle: slot ^= (row>>1)&3, applied as
//    linear LDS dest + inverse-permuted GLOBAL source (rule #21)
//  - bijective XCD swizzle on flattened wgid (grids are %8 == 0)
// ---------------------------------------------------------------------------
template <bool OUT_BF16>
__global__ __launch_bounds__(256) void gemm_bt_kernel(
    const __hip_bfloat16* __restrict__ A, const __hip_bfloat16* __restrict__ B,
    void* __restrict__ Cv, int M, int N, int K) {
  __shared__ __hip_bfloat16 sA[2][128 * 32];
  __shared__ __hip_bfloat16 sB[2][128 * 32];
  const int tid = threadIdx.x;
  const int w = tid >> 6, l = tid & 63;
  const int wr = w >> 1, wc = w & 1;
  const int lr = l & 15;

  const int nbx = gridDim.x;
  const int nwg = nbx * gridDim.y;
  int wgid = blockIdx.y * nbx + blockIdx.x;
  wgid = (wgid & 7) * (nwg >> 3) + (wgid >> 3);  // XCD chunking
  const int brow = (wgid / nbx) * 128;
  const int bcol = (wgid % nbx) * 128;

  f32x4 acc[4][4];
#pragma unroll
  for (int m = 0; m < 4; m++)
#pragma unroll
    for (int n = 0; n < 4; n++) acc[m][n] = (f32x4){0.f, 0.f, 0.f, 0.f};

  // staging: thread tid -> LDS row tid>>2, slot tid&3 (linear dest).
  // that LDS slot semantically holds global slot (tid&3) ^ ((row>>1)&3):
  const int r0 = tid >> 2;
  const int c0s = (((tid & 3) ^ ((tid >> 3) & 3)) << 3);  // inverse-permuted src
  const __hip_bfloat16* Ag = A + (size_t)(brow + r0) * K + c0s;
  const __hip_bfloat16* Bg = B + (size_t)(bcol + r0) * K + c0s;

  // swizzled read slot: true slot l>>4 lives at slot (l>>4) ^ ((row>>1)&3),
  // and (row>>1)&3 == (lr>>1)&3 for all fragment rows.
  const int sw8 = (((l >> 4) ^ ((lr >> 1) & 3)) << 3);

#define STAGE(D, K0)                                                          \
  {                                                                           \
    GLOAD_LDS16(Ag + (K0),                  sA[D] + tid * 8);                 \
    GLOAD_LDS16(Ag + (K0) + (size_t)64 * K, sA[D] + 2048 + tid * 8);          \
    GLOAD_LDS16(Bg + (K0),                  sB[D] + tid * 8);                 \
    GLOAD_LDS16(Bg + (K0) + (size_t)64 * K, sB[D] + 2048 + tid * 8);          \
  }

#define COMPUTE(D)                                                            \
  {                                                                           \
    bf16x8 af[4], bfr[4];                                                     \
    _Pragma("unroll") for (int mm = 0; mm < 4; mm++) af[mm] =                 \
        *(const bf16x8*)&sA[D][(wr * 64 + mm * 16 + lr) * 32 + sw8];          \
    _Pragma("unroll") for (int nn = 0; nn < 4; nn++) bfr[nn] =                \
        *(const bf16x8*)&sB[D][(wc * 64 + nn * 16 + lr) * 32 + sw8];          \
    _Pragma("unroll") for (int mm = 0; mm < 4; mm++)                          \
        _Pragma("unroll") for (int nn = 0; nn < 4; nn++) acc[mm][nn] =        \
        __builtin_amdgcn_mfma_f32_16x16x32_bf16(af[mm], bfr[nn], acc[mm][nn], \
                                                0, 0, 0);                     \
  }

  STAGE(0, 0);
  int k0 = 0;
  for (; k0 + 64 < K; k0 += 64) {
    STAGE(1, k0 + 32);
    asm volatile("s_waitcnt vmcnt(4)" ::: "memory");
    __builtin_amdgcn_s_barrier();
    __builtin_amdgcn_sched_barrier(0);
    COMPUTE(0);
    __builtin_amdgcn_s_barrier();
    __builtin_amdgcn_sched_barrier(0);
    STAGE(0, k0 + 64);
    asm volatile("s_waitcnt vmcnt(4)" ::: "memory");
    __builtin_amdgcn_s_barrier();
    __builtin_amdgcn_sched_barrier(0);
    COMPUTE(1);
    __builtin_amdgcn_s_barrier();
    __builtin_amdgcn_sched_barrier(0);
  }
  // k0 == K - 64: last two tiles, drain once at the very end
  STAGE(1, k0 + 32);
  asm volatile("s_waitcnt vmcnt(4)" ::: "memory");
  __builtin_amdgcn_s_barrier();
  __builtin_amdgcn_sched_barrier(0);
  COMPUTE(0);
  asm volatile("s_waitcnt vmcnt(0)" ::: "memory");
  __builtin_amdgcn_s_barrier();
  __builtin_amdgcn_sched_barrier(0);
  COMPUTE(1);
#undef STAGE
#undef COMPUTE

  const int jr = (l >> 4) << 2;
  if (OUT_BF16) {
    __hip_bfloat16* C = (__hip_bfloat16*)Cv;
#pragma unroll
    for (int m = 0; m < 4; m++)
#pragma unroll
      for (int n = 0; n < 4; n++)
#pragma unroll
        for (int j = 0; j < 4; j++) {
          size_t row = brow + wr * 64 + m * 16 + jr + j;
          size_t col = bcol + wc * 64 + n * 16 + lr;
          C[row * N + col] = __float2bfloat16(acc[m][n][j]);
        }
  } else {
    float* C = (float*)Cv;
#pragma unroll
    for (int m = 0; m < 4; m++)
#pragma unroll
      for (int n = 0; n < 4; n++)
#pragma unroll
        for (int j = 0; j < 4; j++) {
          size_t row = brow + wr * 64 + m * 16 + jr + j;
          size_t col = bcol + wc * 64 + n * 16 + lr;
          C[row * N + col] = acc[m][n][j];
        }
  }
}

// ---------------------------------------------------------------------------
// RoPE (neox) in-place on Q (heads 0..31) and K (heads 32..39) of QKV.
// ---------------------------------------------------------------------------
__global__ void rope_kernel(__hip_bfloat16* __restrict__ QKV,
                            const int* __restrict__ pos) {
  int idx = blockIdx.x * blockDim.x + threadIdx.x;  // S*40*64 total
  int d = idx & 63;
  int head = (idx >> 6) % 40;
  int s = idx / (64 * 40);
  float p = (float)pos[s];
  float inv = exp2f(-(float)d * 0.2076205059304297f);
  float fr = p * inv;
  float sn, cs;
  sincosf(fr, &sn, &cs);
  size_t base = (size_t)s * QKV_LD + head * 128 + d;
  float x1 = __bfloat162float(QKV[base]);
  float x2 = __bfloat162float(QKV[base + 64]);
  QKV[base]      = __float2bfloat16(x1 * cs - x2 * sn);
  QKV[base + 64] = __float2bfloat16(x2 * cs + x1 * sn);
}

// ---------------------------------------------------------------------------
// V transpose: Vt[kvh][d][s] = QKV[s][5120 + kvh*128 + d]
// ---------------------------------------------------------------------------
__global__ void vtrans_kernel(const __hip_bfloat16* __restrict__ QKV,
                              __hip_bfloat16* __restrict__ Vt) {
  int idx = blockIdx.x * blockDim.x + threadIdx.x;  // 8*128*2048
  int s = idx & 2047;
  int d = (idx >> 11) & 127;
  int kh = idx >> 18;
  Vt[idx] = QKV[(size_t)s * QKV_LD + 5120 + kh * 128 + d];
}

// ---------------------------------------------------------------------------
// Causal GQA flash attention (unchanged from R8): swapped-QK 32x32
// zero-staging tiles + split-KV x2.
// ---------------------------------------------------------------------------
__global__ __launch_bounds__(256, 2) void attn_kernel(
    const __hip_bfloat16* __restrict__ QKV,
    const __hip_bfloat16* __restrict__ Vt, __hip_bfloat16* __restrict__ O) {
  __shared__ float Ms[2][64][67];  // [head-slot][lane][64 oacc + m + lsum]
  const int tid = threadIdx.x;
  const int w = tid >> 6, l = tid & 63;
  const int l31 = l & 31;
  const int hiP = l >> 5;
  const int bid = blockIdx.x;
  const int kvh = bid & 7;                 // XCD-resident kv head
  const int hp = (bid >> 3) & 1;           // head pair within kv group
  const int qt = 63 - (bid >> 4);          // longest blocks dispatched first
  const int half = w >> 1;                 // kv-range half
  const int h = kvh * 4 + hp * 2 + (w & 1);
  const int qwb = qt * 32;                 // q base row
  const int qg = qwb + l31;                // this lane's q row

  const __hip_bfloat16* Qp = QKV + (size_t)h * DH;
  const __hip_bfloat16* Kp = QKV + 4096 + (size_t)kvh * DH;
  const __hip_bfloat16* Vp = Vt + (size_t)kvh * (DH * S_SEQ);

  // Q B-frags (held whole kernel): qf[ks] = Q[q=l31][ks*16 + hiP*8 .. +8]
  bf16x8 qf[8];
  {
    const __hip_bfloat16* qrow = Qp + (size_t)(qwb + l31) * QKV_LD + hiP * 8;
#pragma unroll
    for (int ks = 0; ks < 8; ks++) qf[ks] = *(const bf16x8*)(qrow + ks * 16);
  }

  f32x16 oacc[4];
#pragma unroll
  for (int db = 0; db < 4; db++)
#pragma unroll
    for (int r = 0; r < 16; r++) oacc[db][r] = 0.f;
  float m = -1e30f, lsum = 0.f;

#define COMPUTE_TILE(KB, MASKED)                                               \
  {                                                                            \
    const int kb_ = (KB);                                                      \
    f32x16 sacc;                                                               \
    _Pragma("unroll") for (int r = 0; r < 16; r++) sacc[r] = 0.f;              \
    {                                                                          \
      bf16x8 kf[8];                                                            \
      const __hip_bfloat16* krow =                                             \
          Kp + (size_t)(kb_ + l31) * QKV_LD + hiP * 8;                         \
      _Pragma("unroll") for (int ks = 0; ks < 8; ks++) kf[ks] =                \
          *(const bf16x8*)(krow + ks * 16);                                    \
      _Pragma("unroll") for (int ks = 0; ks < 8; ks++) sacc =                  \
          __builtin_amdgcn_mfma_f32_32x32x16_bf16(kf[ks], qf[ks], sacc, 0, 0,  \
                                                  0);                          \
    }                                                                          \
    bf16x8 vf[4][2];                                                           \
    _Pragma("unroll") for (int db = 0; db < 4; db++)                           \
        _Pragma("unroll") for (int k2 = 0; k2 < 2; k2++) vf[db][k2] =          \
        *(const bf16x8*)(Vp + (size_t)(db * 32 + l31) * S_SEQ + kb_ +          \
                         k2 * 16 + hiP * 8);                                   \
    float s[16];                                                               \
    _Pragma("unroll") for (int r = 0; r < 16; r++) s[r] = sacc[r] * C2F;       \
    if (MASKED) {                                                              \
      _Pragma("unroll") for (int r = 0; r < 16; r++) {                         \
        const int kvg = kb_ + (r & 3) + 8 * (r >> 2) + 4 * hiP;                \
        s[r] = (kvg <= qg) ? s[r] : -1e30f;                                    \
      }                                                                        \
    }                                                                          \
    float m0 = fmaxf(fmaxf(s[0], s[1]), fmaxf(s[2], s[3]));                    \
    float m1 = fmaxf(fmaxf(s[4], s[5]), fmaxf(s[6], s[7]));                    \
    float m2 = fmaxf(fmaxf(s[8], s[9]), fmaxf(s[10], s[11]));                  \
    float m3 = fmaxf(fmaxf(s[12], s[13]), fmaxf(s[14], s[15]));                \
    float rmax = fmaxf(fmaxf(m0, m1), fmaxf(m2, m3));                          \
    rmax = fmaxf(rmax, xhalf(rmax, hiP));                                      \
    if (__any(rmax - m > 8.0f)) {                                              \
      float mn = fmaxf(m, rmax);                                               \
      float sc = __builtin_amdgcn_exp2f(m - mn);                               \
      lsum *= sc;                                                              \
      _Pragma("unroll") for (int db = 0; db < 4; db++)                         \
          _Pragma("unroll") for (int r = 0; r < 16; r++) oacc[db][r] *= sc;    \
      m = mn;                                                                  \
    }                                                                          \
    float p[16];                                                               \
    _Pragma("unroll") for (int r = 0; r < 16; r++) p[r] =                      \
        __builtin_amdgcn_exp2f(s[r] - m);                                      \
    float rs = ((p[0] + p[1]) + (p[2] + p[3])) +                               \
               ((p[4] + p[5]) + (p[6] + p[7])) +                               \
               ((p[8] + p[9]) + (p[10] + p[11])) +                             \
               ((p[12] + p[13]) + (p[14] + p[15]));                            \
    lsum += rs + xhalf(rs, hiP);                                               \
    unsigned Wp[8];                                                            \
    _Pragma("unroll") for (int i = 0; i < 8; i++) Wp[i] =                      \
        (unsigned)f2bf_bits(p[2 * i]) |                                        \
        ((unsigned)f2bf_bits(p[2 * i + 1]) << 16);                             \
    unsigned s0x = Wp[0], s0y = Wp[2];                                         \
    unsigned s1x = Wp[1], s1y = Wp[3];                                         \
    unsigned s2x = Wp[4], s2y = Wp[6];                                         \
    unsigned s3x = Wp[5], s3y = Wp[7];                                         \
    plswap(s0x, s0y);                                                          \
    plswap(s1x, s1y);                                                          \
    plswap(s2x, s2y);                                                          \
    plswap(s3x, s3y);                                                          \
    int4 f0, f1;                                                               \
    f0.x = (int)s0x; f0.y = (int)s1x; f0.z = (int)s0y; f0.w = (int)s1y;        \
    f1.x = (int)s2x; f1.y = (int)s3x; f1.z = (int)s2y; f1.w = (int)s3y;        \
    bf16x8 pfrag[2];                                                           \
    pfrag[0] = __builtin_bit_cast(bf16x8, f0);                                 \
    pfrag[1] = __builtin_bit_cast(bf16x8, f1);                                 \
    _Pragma("unroll") for (int db = 0; db < 4; db++)                           \
        _Pragma("unroll") for (int k2 = 0; k2 < 2; k2++) oacc[db] =            \
        __builtin_amdgcn_mfma_f32_32x32x16_bf16(vf[db][k2], pfrag[k2],         \
                                                oacc[db], 0, 0, 0);            \
  }

  const int nt = qt + 1;
  const int nt0 = nt >> 1;  // tiles in half 0 (may be 0)

  if (half) {
    for (int kb = nt0 * 32; kb < qwb; kb += 32) COMPUTE_TILE(kb, false);
    COMPUTE_TILE(qwb, true);
  } else {
    const int kend = nt0 * 32;
    for (int kb = 0; kb < kend; kb += 32) COMPUTE_TILE(kb, false);
  }
#undef COMPUTE_TILE

  // ---- split-KV merge ----
  if (half) {
    float* dst = Ms[w & 1][l];
#pragma unroll
    for (int db = 0; db < 4; db++)
#pragma unroll
      for (int r = 0; r < 16; r++) dst[db * 16 + r] = oacc[db][r];
    dst[64] = m;
    dst[65] = lsum;
  }
  __syncthreads();
  if (!half) {
    const float* src = Ms[w & 1][l];
    const float mB = src[64], lB = src[65];
    const float mS = fmaxf(m, mB);
    float fa = __builtin_amdgcn_exp2f(m - mS);
    float fb = __builtin_amdgcn_exp2f(mB - mS);
    const float inv = 1.0f / (lsum * fa + lB * fb);
    fa *= inv;
    fb *= inv;
    // write O[q][h*128 + d], d = db*32 + 8*rg + 4*hiP + (r&3)
    __hip_bfloat16* orow = O + (size_t)qg * (NQH * DH) + h * DH;
#pragma unroll
    for (int db = 0; db < 4; db++)
#pragma unroll
      for (int rg = 0; rg < 4; rg++) {
        ushort4 u;
        u.x = f2bf_bits(oacc[db][rg * 4 + 0] * fa + src[db * 16 + rg * 4 + 0] * fb);
        u.y = f2bf_bits(oacc[db][rg * 4 + 1] * fa + src[db * 16 + rg * 4 + 1] * fb);
        u.z = f2bf_bits(oacc[db][rg * 4 + 2] * fa + src[db * 16 + rg * 4 + 2] * fb);
        u.w = f2bf_bits(oacc[db][rg * 4 + 3] * fa + src[db * 16 + rg * 4 + 3] * fb);
        *reinterpret_cast<ushort4*>(orow + db * 32 + 8 * rg + 4 * hiP) = u;
      }
  }
}

// ---------------------------------------------------------------------------
extern "C" void kernel_launch(void* const* d_in, const int* in_sizes, int n_in,
                              void* d_out, int out_size, void* d_ws,
                              size_t ws_size, hipStream_t stream) {
  const float* hs = (const float*)d_in[0];
  const int* pos = (const int*)d_in[1];
  const float* wqkv = (const float*)d_in[2];
  const float* wo = (const float*)d_in[3];
  float* out = (float*)d_out;

  char* ws = (char*)d_ws;
  __hip_bfloat16* Xb      = (__hip_bfloat16*)(ws);                // 16 MB
  __hip_bfloat16* Wqkvb   = (__hip_bfloat16*)(ws + 16777216);     // 48 MB
  __hip_bfloat16* Wob     = (__hip_bfloat16*)(ws + 67108864);     // 32 MB
  __hip_bfloat16* QKV     = (__hip_bfloat16*)(ws + 100663296);    // 24 MB
  __hip_bfloat16* AttnOut = (__hip_bfloat16*)(ws + 125829120);    // 16 MB
  __hip_bfloat16* Vt      = (__hip_bfloat16*)(ws + 142606336);    // 4 MB

  cvt_f32_bf16<<<2048, 256, 0, stream>>>(hs, Xb, S_SEQ * HID);
  cvt_f32_bf16<<<2048, 256, 0, stream>>>(wqkv, Wqkvb, QKV_LD * HID);
  cvt_f32_bf16<<<2048, 256, 0, stream>>>(wo, Wob, HID * HID);

  gemm_bt_kernel<true><<<dim3(QKV_LD / 128, S_SEQ / 128), 256, 0, stream>>>(
      Xb, Wqkvb, QKV, S_SEQ, QKV_LD, HID);

  rope_kernel<<<(S_SEQ * 40 * 64) / 256, 256, 0, stream>>>(QKV, pos);
  vtrans_kernel<<<(NKVH * DH * S_SEQ) / 256, 256, 0, stream>>>(QKV, Vt);

  attn_kernel<<<1024, 256, 0, stream>>>(QKV, Vt, AttnOut);

  gemm_bt_kernel<false><<<dim3(HID / 128, S_SEQ / 128), 256, 0, stream>>>(
      AttnOut, Wob, out, S_SEQ, HID, HID);
}

// Round 11
// 329.391 us; speedup vs baseline: 2.6213x; 1.2572x over previous
//
#include <hip/hip_runtime.h>
#include <hip/hip_bf16.h>
#include <cstdint>

#define S_SEQ   2048
#define HID     4096
#define NQH     32
#define NKVH    8
#define DH      128
#define QKV_LD  6144      // (32+16)*128
#define SCALE_F 0.08838834764831845f
// softmax in log2 domain: s' = s * SCALE * log2(e)
#define C2F (0.08838834764831845f * 1.4426950408889634f)

using f32x4  = __attribute__((ext_vector_type(4))) float;
using f32x16 = __attribute__((ext_vector_type(16))) float;
using bf16x8 = __attribute__((ext_vector_type(8))) __bf16;
using u32x2  = __attribute__((ext_vector_type(2))) unsigned;

#define GLOAD_LDS16(gp, lp)                                                   \
  __builtin_amdgcn_global_load_lds(                                           \
      (__attribute__((address_space(1))) const void*)(gp),                    \
      (__attribute__((address_space(3))) void*)(lp), 16, 0, 0)

__device__ __forceinline__ unsigned short f2bf_bits(float f) {
  __hip_bfloat16 b = __float2bfloat16(f);
  return __builtin_bit_cast(unsigned short, b);
}

// permlane32_swap: X[32..63] <-> Y[0..31].
__device__ __forceinline__ void plswap(unsigned& x, unsigned& y) {
  u32x2 r = __builtin_amdgcn_permlane32_swap(x, y, false, false);
  x = r[0];
  y = r[1];
}
// value of the partner lane (l ^ 32)
__device__ __forceinline__ float xhalf(float v, int hiP) {
  unsigned u = __builtin_bit_cast(unsigned, v);
  u32x2 r = __builtin_amdgcn_permlane32_swap(u, u, false, false);
  return __builtin_bit_cast(float, hiP ? r[0] : r[1]);
}

// ---------------------------------------------------------------------------
// f32 -> bf16 conversion (vectorized, grid-stride)
// ---------------------------------------------------------------------------
__global__ void cvt_f32_bf16(const float* __restrict__ in,
                             __hip_bfloat16* __restrict__ out, int n) {
  int i = blockIdx.x * blockDim.x + threadIdx.x;
  int stride = gridDim.x * blockDim.x;
  for (int e = i * 4; e < n; e += stride * 4) {
    float4 v = *(const float4*)(in + e);
    ushort4 u;
    u.x = f2bf_bits(v.x); u.y = f2bf_bits(v.y);
    u.z = f2bf_bits(v.z); u.w = f2bf_bits(v.w);
    *reinterpret_cast<ushort4*>(reinterpret_cast<unsigned short*>(out) + e) = u;
  }
}

// ---------------------------------------------------------------------------
// GEMM: C[M,N] = A[M,K] * B[N,K]^T  (unchanged from R10: 2-phase pipelined,
// LDS dbuf, counted vmcnt(4), slot swizzle, XCD swizzle)
// ---------------------------------------------------------------------------
template <bool OUT_BF16>
__global__ __launch_bounds__(256) void gemm_bt_kernel(
    const __hip_bfloat16* __restrict__ A, const __hip_bfloat16* __restrict__ B,
    void* __restrict__ Cv, int M, int N, int K) {
  __shared__ __hip_bfloat16 sA[2][128 * 32];
  __shared__ __hip_bfloat16 sB[2][128 * 32];
  const int tid = threadIdx.x;
  const int w = tid >> 6, l = tid & 63;
  const int wr = w >> 1, wc = w & 1;
  const int lr = l & 15;

  const int nbx = gridDim.x;
  const int nwg = nbx * gridDim.y;
  int wgid = blockIdx.y * nbx + blockIdx.x;
  wgid = (wgid & 7) * (nwg >> 3) + (wgid >> 3);  // XCD chunking
  const int brow = (wgid / nbx) * 128;
  const int bcol = (wgid % nbx) * 128;

  f32x4 acc[4][4];
#pragma unroll
  for (int m = 0; m < 4; m++)
#pragma unroll
    for (int n = 0; n < 4; n++) acc[m][n] = (f32x4){0.f, 0.f, 0.f, 0.f};

  const int r0 = tid >> 2;
  const int c0s = (((tid & 3) ^ ((tid >> 3) & 3)) << 3);  // inverse-permuted src
  const __hip_bfloat16* Ag = A + (size_t)(brow + r0) * K + c0s;
  const __hip_bfloat16* Bg = B + (size_t)(bcol + r0) * K + c0s;

  const int sw8 = (((l >> 4) ^ ((lr >> 1) & 3)) << 3);

#define STAGE(D, K0)                                                          \
  {                                                                           \
    GLOAD_LDS16(Ag + (K0),                  sA[D] + tid * 8);                 \
    GLOAD_LDS16(Ag + (K0) + (size_t)64 * K, sA[D] + 2048 + tid * 8);          \
    GLOAD_LDS16(Bg + (K0),                  sB[D] + tid * 8);                 \
    GLOAD_LDS16(Bg + (K0) + (size_t)64 * K, sB[D] + 2048 + tid * 8);          \
  }

#define COMPUTE(D)                                                            \
  {                                                                           \
    bf16x8 af[4], bfr[4];                                                     \
    _Pragma("unroll") for (int mm = 0; mm < 4; mm++) af[mm] =                 \
        *(const bf16x8*)&sA[D][(wr * 64 + mm * 16 + lr) * 32 + sw8];          \
    _Pragma("unroll") for (int nn = 0; nn < 4; nn++) bfr[nn] =                \
        *(const bf16x8*)&sB[D][(wc * 64 + nn * 16 + lr) * 32 + sw8];          \
    _Pragma("unroll") for (int mm = 0; mm < 4; mm++)                          \
        _Pragma("unroll") for (int nn = 0; nn < 4; nn++) acc[mm][nn] =        \
        __builtin_amdgcn_mfma_f32_16x16x32_bf16(af[mm], bfr[nn], acc[mm][nn], \
                                                0, 0, 0);                     \
  }

  STAGE(0, 0);
  int k0 = 0;
  for (; k0 + 64 < K; k0 += 64) {
    STAGE(1, k0 + 32);
    asm volatile("s_waitcnt vmcnt(4)" ::: "memory");
    __builtin_amdgcn_s_barrier();
    __builtin_amdgcn_sched_barrier(0);
    COMPUTE(0);
    __builtin_amdgcn_s_barrier();
    __builtin_amdgcn_sched_barrier(0);
    STAGE(0, k0 + 64);
    asm volatile("s_waitcnt vmcnt(4)" ::: "memory");
    __builtin_amdgcn_s_barrier();
    __builtin_amdgcn_sched_barrier(0);
    COMPUTE(1);
    __builtin_amdgcn_s_barrier();
    __builtin_amdgcn_sched_barrier(0);
  }
  STAGE(1, k0 + 32);
  asm volatile("s_waitcnt vmcnt(4)" ::: "memory");
  __builtin_amdgcn_s_barrier();
  __builtin_amdgcn_sched_barrier(0);
  COMPUTE(0);
  asm volatile("s_waitcnt vmcnt(0)" ::: "memory");
  __builtin_amdgcn_s_barrier();
  __builtin_amdgcn_sched_barrier(0);
  COMPUTE(1);
#undef STAGE
#undef COMPUTE

  const int jr = (l >> 4) << 2;
  if (OUT_BF16) {
    __hip_bfloat16* C = (__hip_bfloat16*)Cv;
#pragma unroll
    for (int m = 0; m < 4; m++)
#pragma unroll
      for (int n = 0; n < 4; n++)
#pragma unroll
        for (int j = 0; j < 4; j++) {
          size_t row = brow + wr * 64 + m * 16 + jr + j;
          size_t col = bcol + wc * 64 + n * 16 + lr;
          C[row * N + col] = __float2bfloat16(acc[m][n][j]);
        }
  } else {
    float* C = (float*)Cv;
#pragma unroll
    for (int m = 0; m < 4; m++)
#pragma unroll
      for (int n = 0; n < 4; n++)
#pragma unroll
        for (int j = 0; j < 4; j++) {
          size_t row = brow + wr * 64 + m * 16 + jr + j;
          size_t col = bcol + wc * 64 + n * 16 + lr;
          C[row * N + col] = acc[m][n][j];
        }
  }
}

// ---------------------------------------------------------------------------
// RoPE (neox) in-place on Q (heads 0..31) and K (heads 32..39) of QKV.
// ---------------------------------------------------------------------------
__global__ void rope_kernel(__hip_bfloat16* __restrict__ QKV,
                            const int* __restrict__ pos) {
  int idx = blockIdx.x * blockDim.x + threadIdx.x;  // S*40*64 total
  int d = idx & 63;
  int head = (idx >> 6) % 40;
  int s = idx / (64 * 40);
  float p = (float)pos[s];
  float inv = exp2f(-(float)d * 0.2076205059304297f);
  float fr = p * inv;
  float sn, cs;
  sincosf(fr, &sn, &cs);
  size_t base = (size_t)s * QKV_LD + head * 128 + d;
  float x1 = __bfloat162float(QKV[base]);
  float x2 = __bfloat162float(QKV[base + 64]);
  QKV[base]      = __float2bfloat16(x1 * cs - x2 * sn);
  QKV[base + 64] = __float2bfloat16(x2 * cs + x1 * sn);
}

// ---------------------------------------------------------------------------
// Pack K and V into fragment-ordered buffers so attn loads are coalesced.
//   Kf element (kvh,t,ks,lane,j)       = K[kvh][t*32+(lane&31)][ks*16+(lane>>5)*8+j]
//   Vf element (kvh,t,slot=db*2+k2,lane,j) = V[kvh][t*32+k2*16+(lane>>5)*8+j][db*32+(lane&31)]
// 16B chunk id o: lane=o&63, slot=(o>>6)&7, t=(o>>9)&63, kvh=(o>>15)&7, K/V=o>>18.
// ---------------------------------------------------------------------------
__global__ void packkv_kernel(const __hip_bfloat16* __restrict__ QKV,
                              __hip_bfloat16* __restrict__ Kf,
                              __hip_bfloat16* __restrict__ Vf) {
  int o = blockIdx.x * blockDim.x + threadIdx.x;  // 2 * 2^18 chunks
  const int lane = o & 63;
  const int slot = (o >> 6) & 7;
  const int t    = (o >> 9) & 63;
  const int kvh  = (o >> 15) & 7;
  const int off8 = (o & 0x3FFFF) * 8;
  if (o < (1 << 18)) {
    // K: contiguous 8 along d
    const int s  = t * 32 + (lane & 31);
    const int d0 = slot * 16 + (lane >> 5) * 8;
    bf16x8 v = *(const bf16x8*)(QKV + (size_t)s * QKV_LD + 4096 + kvh * DH + d0);
    *(bf16x8*)(Kf + off8) = v;
  } else {
    // V: gather 8 along s at fixed d (transpose)
    const int s0 = t * 32 + (slot & 1) * 16 + (lane >> 5) * 8;
    const int d  = (slot >> 1) * 32 + (lane & 31);
    const __hip_bfloat16* src = QKV + (size_t)s0 * QKV_LD + 5120 + kvh * DH + d;
    ushort4 a, b;
    a.x = __builtin_bit_cast(unsigned short, src[0 * QKV_LD]);
    a.y = __builtin_bit_cast(unsigned short, src[1 * QKV_LD]);
    a.z = __builtin_bit_cast(unsigned short, src[2 * QKV_LD]);
    a.w = __builtin_bit_cast(unsigned short, src[3 * QKV_LD]);
    b.x = __builtin_bit_cast(unsigned short, src[4 * QKV_LD]);
    b.y = __builtin_bit_cast(unsigned short, src[5 * QKV_LD]);
    b.z = __builtin_bit_cast(unsigned short, src[6 * QKV_LD]);
    b.w = __builtin_bit_cast(unsigned short, src[7 * QKV_LD]);
    *(ushort4*)(Vf + off8)     = a;
    *(ushort4*)(Vf + off8 + 4) = b;
  }
}

// ---------------------------------------------------------------------------
// Causal GQA flash attention: swapped-QK 32x32 + split-KV x2 (R8 structure),
// K/V fragment loads now fully coalesced from Kf/Vf.
// ---------------------------------------------------------------------------
__global__ __launch_bounds__(256, 2) void attn_kernel(
    const __hip_bfloat16* __restrict__ QKV, const __hip_bfloat16* __restrict__ Kf,
    const __hip_bfloat16* __restrict__ Vf, __hip_bfloat16* __restrict__ O) {
  __shared__ float Ms[2][64][67];  // [head-slot][lane][64 oacc + m + lsum]
  const int tid = threadIdx.x;
  const int w = tid >> 6, l = tid & 63;
  const int l31 = l & 31;
  const int hiP = l >> 5;
  const int bid = blockIdx.x;
  const int kvh = bid & 7;                 // XCD-resident kv head
  const int hp = (bid >> 3) & 1;           // head pair within kv group
  const int qt = 63 - (bid >> 4);          // longest blocks dispatched first
  const int half = w >> 1;                 // kv-range half
  const int h = kvh * 4 + hp * 2 + (w & 1);
  const int qwb = qt * 32;                 // q base row
  const int qg = qwb + l31;                // this lane's q row

  const __hip_bfloat16* Qp  = QKV + (size_t)h * DH;
  const __hip_bfloat16* Kfp = Kf + (size_t)kvh * 262144 + l * 8;
  const __hip_bfloat16* Vfp = Vf + (size_t)kvh * 262144 + l * 8;

  // Q B-frags (held whole kernel): qf[ks] = Q[q=l31][ks*16 + hiP*8 .. +8]
  bf16x8 qf[8];
  {
    const __hip_bfloat16* qrow = Qp + (size_t)(qwb + l31) * QKV_LD + hiP * 8;
#pragma unroll
    for (int ks = 0; ks < 8; ks++) qf[ks] = *(const bf16x8*)(qrow + ks * 16);
  }

  f32x16 oacc[4];
#pragma unroll
  for (int db = 0; db < 4; db++)
#pragma unroll
    for (int r = 0; r < 16; r++) oacc[db][r] = 0.f;
  float m = -1e30f, lsum = 0.f;

#define COMPUTE_TILE(KB, MASKED)                                               \
  {                                                                            \
    const int kb_ = (KB);                                                      \
    const int toff_ = (kb_ >> 5) * 4096;                                       \
    f32x16 sacc;                                                               \
    _Pragma("unroll") for (int r = 0; r < 16; r++) sacc[r] = 0.f;              \
    {                                                                          \
      bf16x8 kf[8];                                                            \
      _Pragma("unroll") for (int ks = 0; ks < 8; ks++) kf[ks] =                \
          *(const bf16x8*)(Kfp + toff_ + ks * 512);                            \
      _Pragma("unroll") for (int ks = 0; ks < 8; ks++) sacc =                  \
          __builtin_amdgcn_mfma_f32_32x32x16_bf16(kf[ks], qf[ks], sacc, 0, 0,  \
                                                  0);                          \
    }                                                                          \
    bf16x8 vf[4][2];                                                           \
    _Pragma("unroll") for (int db = 0; db < 4; db++)                           \
        _Pragma("unroll") for (int k2 = 0; k2 < 2; k2++) vf[db][k2] =          \
        *(const bf16x8*)(Vfp + toff_ + (db * 2 + k2) * 512);                   \
    float s[16];                                                               \
    _Pragma("unroll") for (int r = 0; r < 16; r++) s[r] = sacc[r] * C2F;       \
    if (MASKED) {                                                              \
      _Pragma("unroll") for (int r = 0; r < 16; r++) {                         \
        const int kvg = kb_ + (r & 3) + 8 * (r >> 2) + 4 * hiP;                \
        s[r] = (kvg <= qg) ? s[r] : -1e30f;                                    \
      }                                                                        \
    }                                                                          \
    float m0 = fmaxf(fmaxf(s[0], s[1]), fmaxf(s[2], s[3]));                    \
    float m1 = fmaxf(fmaxf(s[4], s[5]), fmaxf(s[6], s[7]));                    \
    float m2 = fmaxf(fmaxf(s[8], s[9]), fmaxf(s[10], s[11]));                  \
    float m3 = fmaxf(fmaxf(s[12], s[13]), fmaxf(s[14], s[15]));                \
    float rmax = fmaxf(fmaxf(m0, m1), fmaxf(m2, m3));                          \
    rmax = fmaxf(rmax, xhalf(rmax, hiP));                                      \
    if (__any(rmax - m > 8.0f)) {                                              \
      float mn = fmaxf(m, rmax);                                               \
      float sc = __builtin_amdgcn_exp2f(m - mn);                               \
      lsum *= sc;                                                              \
      _Pragma("unroll") for (int db = 0; db < 4; db++)                         \
          _Pragma("unroll") for (int r = 0; r < 16; r++) oacc[db][r] *= sc;    \
      m = mn;                                                                  \
    }                                                                          \
    float p[16];                                                               \
    _Pragma("unroll") for (int r = 0; r < 16; r++) p[r] =                      \
        __builtin_amdgcn_exp2f(s[r] - m);                                      \
    float rs = ((p[0] + p[1]) + (p[2] + p[3])) +                               \
               ((p[4] + p[5]) + (p[6] + p[7])) +                               \
               ((p[8] + p[9]) + (p[10] + p[11])) +                             \
               ((p[12] + p[13]) + (p[14] + p[15]));                            \
    lsum += rs + xhalf(rs, hiP);                                               \
    unsigned Wp[8];                                                            \
    _Pragma("unroll") for (int i = 0; i < 8; i++) Wp[i] =                      \
        (unsigned)f2bf_bits(p[2 * i]) |                                        \
        ((unsigned)f2bf_bits(p[2 * i + 1]) << 16);                             \
    unsigned s0x = Wp[0], s0y = Wp[2];                                         \
    unsigned s1x = Wp[1], s1y = Wp[3];                                         \
    unsigned s2x = Wp[4], s2y = Wp[6];                                         \
    unsigned s3x = Wp[5], s3y = Wp[7];                                         \
    plswap(s0x, s0y);                                                          \
    plswap(s1x, s1y);                                                          \
    plswap(s2x, s2y);                                                          \
    plswap(s3x, s3y);                                                          \
    int4 f0, f1;                                                               \
    f0.x = (int)s0x; f0.y = (int)s1x; f0.z = (int)s0y; f0.w = (int)s1y;        \
    f1.x = (int)s2x; f1.y = (int)s3x; f1.z = (int)s2y; f1.w = (int)s3y;        \
    bf16x8 pfrag[2];                                                           \
    pfrag[0] = __builtin_bit_cast(bf16x8, f0);                                 \
    pfrag[1] = __builtin_bit_cast(bf16x8, f1);                                 \
    _Pragma("unroll") for (int db = 0; db < 4; db++)                           \
        _Pragma("unroll") for (int k2 = 0; k2 < 2; k2++) oacc[db] =            \
        __builtin_amdgcn_mfma_f32_32x32x16_bf16(vf[db][k2], pfrag[k2],         \
                                                oacc[db], 0, 0, 0);            \
  }

  const int nt = qt + 1;
  const int nt0 = nt >> 1;  // tiles in half 0 (may be 0)

  if (half) {
    for (int kb = nt0 * 32; kb < qwb; kb += 32) COMPUTE_TILE(kb, false);
    COMPUTE_TILE(qwb, true);
  } else {
    const int kend = nt0 * 32;
    for (int kb = 0; kb < kend; kb += 32) COMPUTE_TILE(kb, false);
  }
#undef COMPUTE_TILE

  // ---- split-KV merge ----
  if (half) {
    float* dst = Ms[w & 1][l];
#pragma unroll
    for (int db = 0; db < 4; db++)
#pragma unroll
      for (int r = 0; r < 16; r++) dst[db * 16 + r] = oacc[db][r];
    dst[64] = m;
    dst[65] = lsum;
  }
  __syncthreads();
  if (!half) {
    const float* src = Ms[w & 1][l];
    const float mB = src[64], lB = src[65];
    const float mS = fmaxf(m, mB);
    float fa = __builtin_amdgcn_exp2f(m - mS);
    float fb = __builtin_amdgcn_exp2f(mB - mS);
    const float inv = 1.0f / (lsum * fa + lB * fb);
    fa *= inv;
    fb *= inv;
    // write O[q][h*128 + d], d = db*32 + 8*rg + 4*hiP + (r&3)
    __hip_bfloat16* orow = O + (size_t)qg * (NQH * DH) + h * DH;
#pragma unroll
    for (int db = 0; db < 4; db++)
#pragma unroll
      for (int rg = 0; rg < 4; rg++) {
        ushort4 u;
        u.x = f2bf_bits(oacc[db][rg * 4 + 0] * fa + src[db * 16 + rg * 4 + 0] * fb);
        u.y = f2bf_bits(oacc[db][rg * 4 + 1] * fa + src[db * 16 + rg * 4 + 1] * fb);
        u.z = f2bf_bits(oacc[db][rg * 4 + 2] * fa + src[db * 16 + rg * 4 + 2] * fb);
        u.w = f2bf_bits(oacc[db][rg * 4 + 3] * fa + src[db * 16 + rg * 4 + 3] * fb);
        *reinterpret_cast<ushort4*>(orow + db * 32 + 8 * rg + 4 * hiP) = u;
      }
  }
}

// ---------------------------------------------------------------------------
extern "C" void kernel_launch(void* const* d_in, const int* in_sizes, int n_in,
                              void* d_out, int out_size, void* d_ws,
                              size_t ws_size, hipStream_t stream) {
  const float* hs = (const float*)d_in[0];
  const int* pos = (const int*)d_in[1];
  const float* wqkv = (const float*)d_in[2];
  const float* wo = (const float*)d_in[3];
  float* out = (float*)d_out;

  char* ws = (char*)d_ws;
  __hip_bfloat16* Xb      = (__hip_bfloat16*)(ws);                // 16 MB
  __hip_bfloat16* Wqkvb   = (__hip_bfloat16*)(ws + 16777216);     // 48 MB
  __hip_bfloat16* Wob     = (__hip_bfloat16*)(ws + 67108864);     // 32 MB
  __hip_bfloat16* QKV     = (__hip_bfloat16*)(ws + 100663296);    // 24 MB
  __hip_bfloat16* AttnOut = (__hip_bfloat16*)(ws + 125829120);    // 16 MB
  __hip_bfloat16* Kf      = (__hip_bfloat16*)(ws + 142606336);    // 4 MB
  __hip_bfloat16* Vf      = (__hip_bfloat16*)(ws);                // 4 MB (Xb dead after gemm1)

  cvt_f32_bf16<<<2048, 256, 0, stream>>>(hs, Xb, S_SEQ * HID);
  cvt_f32_bf16<<<2048, 256, 0, stream>>>(wqkv, Wqkvb, QKV_LD * HID);
  cvt_f32_bf16<<<2048, 256, 0, stream>>>(wo, Wob, HID * HID);

  gemm_bt_kernel<true><<<dim3(QKV_LD / 128, S_SEQ / 128), 256, 0, stream>>>(
      Xb, Wqkvb, QKV, S_SEQ, QKV_LD, HID);

  rope_kernel<<<(S_SEQ * 40 * 64) / 256, 256, 0, stream>>>(QKV, pos);
  packkv_kernel<<<2048, 256, 0, stream>>>(QKV, Kf, Vf);

  attn_kernel<<<1024, 256, 0, stream>>>(QKV, Kf, Vf, AttnOut);

  gemm_bt_kernel<false><<<dim3(HID / 128, S_SEQ / 128), 256, 0, stream>>>(
      AttnOut, Wob, out, S_SEQ, HID, HID);
}